// Round 4
// baseline (729.697 us; speedup 1.0000x reference)
//
#include <hip/hip_runtime.h>
#include <math.h>

// bf16-MFMA decoder, round 4.
// Attention rewritten barrier-free: V pre-transposed to global Vt[(bh)][d][key]
// so PV B-frags are contiguous global loads (L2-resident); no block-shared LDS,
// no __syncthreads; K-split=2 + combine pass for 2x occupancy.

#define D_MODEL 512
#define LQ 1024
#define LKK 2048
#define BB 4
#define NL 3
#define KSPLIT 2
#define NROWS 32768   // packed q-rows total = B*8*1024

typedef __bf16 bf16;
typedef __bf16 bf16x8 __attribute__((ext_vector_type(8)));
typedef __bf16 bf16x4 __attribute__((ext_vector_type(4)));
typedef float f32x4 __attribute__((ext_vector_type(4)));

__device__ inline f32x4 mfma16(bf16x8 a, bf16x8 b, f32x4 c) {
    return __builtin_amdgcn_mfma_f32_16x16x32_bf16(a, b, c, 0, 0, 0);
}

__device__ inline void gload16(const void* g, void* l) {
    __builtin_amdgcn_global_load_lds(
        (const __attribute__((address_space(1))) void*)g,
        (__attribute__((address_space(3))) void*)l, 16, 0, 0);
}

// ---------------- cast fp32 -> bf16 ----------------
__global__ __launch_bounds__(256) void cast_kernel(
    const float* __restrict__ in, bf16* __restrict__ out, long n)
{
    long i4 = ((long)blockIdx.x * 256 + threadIdx.x) * 4;
    if (i4 >= n) return;
    float4 v = *(const float4*)(in + i4);
    bf16x4 o;
    o[0] = (bf16)v.x; o[1] = (bf16)v.y; o[2] = (bf16)v.z; o[3] = (bf16)v.w;
    *(bf16x4*)(out + i4) = o;
}

// ------- transpose-cast W[512][512] fp32 -> bf16 NT, strided dst per z -------
__global__ __launch_bounds__(256) void tcast_kernel(
    const float* __restrict__ in, bf16* __restrict__ out, long dstride)
{
    __shared__ float t[32][33];
    const float* ip = in + (long)blockIdx.z * 262144;
    bf16* op = out + (long)blockIdx.z * dstride;
    int tx = threadIdx.x & 31, ty = threadIdx.x >> 5;
    int x0 = blockIdx.x * 32, y0 = blockIdx.y * 32;
#pragma unroll
    for (int i = 0; i < 4; i++)
        t[ty + 8 * i][tx] = ip[(long)(y0 + ty + 8 * i) * 512 + x0 + tx];
    __syncthreads();
#pragma unroll
    for (int i = 0; i < 4; i++)
        op[(long)(x0 + ty + 8 * i) * 512 + y0 + tx] = (bf16)t[tx][ty + 8 * i];
}

// ------------- mask (int32) -> packed bits -------------
__global__ __launch_bounds__(256) void maskbits_kernel(
    const int* __restrict__ m, unsigned* __restrict__ bits)
{
    long i = (long)blockIdx.x * 256 + threadIdx.x;
    int v = m[i] != 0;
    unsigned long long bal = __ballot(v);
    int lane = threadIdx.x & 63;
    if (lane == 0) bits[i >> 5] = (unsigned)bal;
    else if (lane == 32) bits[i >> 5] = (unsigned)(bal >> 32);
}

// ------------- V transpose: v[(bh)*2048+p][64] -> vt[(bh)*64+d][2048] -------------
__global__ __launch_bounds__(256) void vtrans_kernel(
    const bf16* __restrict__ v, bf16* __restrict__ vt)
{
    __shared__ bf16 t[64][72];
    int bh = blockIdx.y;
    int p0 = blockIdx.x * 64;
    const bf16* vb = v + ((long)bh * 2048 + p0) * 64;
    bf16* vtb = vt + (long)bh * 64 * 2048;
    int tid = threadIdx.x;
#pragma unroll
    for (int it = 0; it < 2; it++) {
        int r = it * 32 + (tid >> 3);
        int c8 = (tid & 7) * 8;
        bf16x8 vv = *(const bf16x8*)(vb + (long)r * 64 + c8);
        *(bf16x8*)&t[r][c8] = vv;
    }
    __syncthreads();
#pragma unroll
    for (int it = 0; it < 2; it++) {
        int d = it * 32 + (tid >> 3);
        int p8 = (tid & 7) * 8;
        bf16x8 ov;
#pragma unroll
        for (int j = 0; j < 8; j++) ov[j] = t[p8 + j][d];
        *(bf16x8*)(vtb + (long)d * 2048 + p0 + p8) = ov;
    }
}

// ------------- 128x64 MFMA GEMM (projections) -------------
template<int BIAS, int RELU, int OUT_BF16>
__global__ __launch_bounds__(256) void mfma_gemm(
    const bf16* __restrict__ A, const bf16* __restrict__ Bt,
    const float* __restrict__ bias, void* __restrict__ Cv,
    int N, int K, float scale, long sA, long sB, long sC)
{
    __shared__ bf16 As[128][32];
    __shared__ bf16 Bs[64][32];
    int tid = threadIdx.x;
    int lane = tid & 63, w = tid >> 6;
    int wr = w >> 1, wc = w & 1;
    int g = lane >> 4, c = lane & 15;
    long z = blockIdx.z;
    const bf16* Ab = A + z * sA;
    const bf16* Bb = Bt + z * sB;
    long row0 = (long)blockIdx.y * 128;
    int n0 = blockIdx.x * 64;

    f32x4 acc[4][2];
#pragma unroll
    for (int m = 0; m < 4; m++)
#pragma unroll
        for (int n = 0; n < 2; n++) acc[m][n] = (f32x4){0.f, 0.f, 0.f, 0.f};

    for (int k0 = 0; k0 < K; k0 += 32) {
        __syncthreads();
        const bf16* ga = Ab + (row0 + w * 32 + (lane >> 2)) * K + k0 + (lane & 3) * 8;
        gload16(ga, &As[w * 32][0]);
        gload16(ga + (long)16 * K, &As[w * 32 + 16][0]);
        const bf16* gb = Bb + (long)(n0 + w * 16 + (lane >> 2)) * K + k0 + (lane & 3) * 8;
        gload16(gb, &Bs[w * 16][0]);
        __syncthreads();
        bf16x8 af[4], bfr[2];
#pragma unroll
        for (int m = 0; m < 4; m++)
            af[m] = *(const bf16x8*)&As[wr * 64 + m * 16 + c][g * 8];
#pragma unroll
        for (int n = 0; n < 2; n++)
            bfr[n] = *(const bf16x8*)&Bs[wc * 32 + n * 16 + c][g * 8];
#pragma unroll
        for (int m = 0; m < 4; m++)
#pragma unroll
            for (int n = 0; n < 2; n++)
                acc[m][n] = mfma16(af[m], bfr[n], acc[m][n]);
    }

    float bv[2] = {0.f, 0.f};
    if (BIAS) {
#pragma unroll
        for (int n = 0; n < 2; n++) bv[n] = bias[n0 + wc * 32 + n * 16 + c];
    }
    float* Cf = (float*)Cv + z * sC;
    bf16* Cb = (bf16*)Cv + z * sC;
#pragma unroll
    for (int m = 0; m < 4; m++)
#pragma unroll
        for (int n = 0; n < 2; n++)
#pragma unroll
            for (int j = 0; j < 4; j++) {
                long row = row0 + wr * 64 + m * 16 + g * 4 + j;
                int col = n0 + wc * 32 + n * 16 + c;
                float v = acc[m][n][j] * scale;
                if (BIAS) v += bv[n];
                if (RELU) v = fmaxf(v, 0.f);
                if (OUT_BF16) Cb[row * N + col] = (bf16)v;
                else Cf[row * N + col] = v;
            }
}

// ------------- 128x128 MFMA GEMM (big GEMMs) -------------
template<int OUT_BF16>
__global__ __launch_bounds__(256) void mfma_gemm128(
    const bf16* __restrict__ A, const bf16* __restrict__ Bt,
    void* __restrict__ Cv, int N, int K, float scale,
    long sA, long sB, long sC)
{
    __shared__ bf16 As[128][32];
    __shared__ bf16 Bs[128][32];
    int tid = threadIdx.x;
    int lane = tid & 63, w = tid >> 6;
    int wr = w >> 1, wc = w & 1;
    int g = lane >> 4, c = lane & 15;
    long z = blockIdx.z;
    const bf16* Ab = A + z * sA;
    const bf16* Bb = Bt + z * sB;
    long row0 = (long)blockIdx.y * 128;
    int n0 = blockIdx.x * 128;

    f32x4 acc[4][4];
#pragma unroll
    for (int m = 0; m < 4; m++)
#pragma unroll
        for (int n = 0; n < 4; n++) acc[m][n] = (f32x4){0.f, 0.f, 0.f, 0.f};

    for (int k0 = 0; k0 < K; k0 += 32) {
        __syncthreads();
        const bf16* ga = Ab + (row0 + w * 16 + (lane >> 2)) * K + k0 + (lane & 3) * 8;
        gload16(ga, &As[w * 16][0]);
        gload16(ga + (long)64 * K, &As[w * 16 + 64][0]);
        const bf16* gb = Bb + (long)(n0 + w * 16 + (lane >> 2)) * K + k0 + (lane & 3) * 8;
        gload16(gb, &Bs[w * 16][0]);
        gload16(gb + (long)64 * K, &Bs[w * 16 + 64][0]);
        __syncthreads();
        bf16x8 af[4], bfr[4];
#pragma unroll
        for (int m = 0; m < 4; m++)
            af[m] = *(const bf16x8*)&As[wr * 64 + m * 16 + c][g * 8];
#pragma unroll
        for (int n = 0; n < 4; n++)
            bfr[n] = *(const bf16x8*)&Bs[wc * 64 + n * 16 + c][g * 8];
#pragma unroll
        for (int m = 0; m < 4; m++)
#pragma unroll
            for (int n = 0; n < 4; n++)
                acc[m][n] = mfma16(af[m], bfr[n], acc[m][n]);
    }

    float* Cf = (float*)Cv + z * sC;
    bf16* Cb = (bf16*)Cv + z * sC;
#pragma unroll
    for (int m = 0; m < 4; m++)
#pragma unroll
        for (int n = 0; n < 4; n++)
#pragma unroll
            for (int j = 0; j < 4; j++) {
                long row = row0 + wr * 64 + m * 16 + g * 4 + j;
                int col = n0 + wc * 64 + n * 16 + c;
                float v = acc[m][n][j] * scale;
                if (OUT_BF16) Cb[row * N + col] = (bf16)v;
                else Cf[row * N + col] = v;
            }
}

// ------------- barrier-free MFMA flash attention (k-split) -------------
// Grid (LQ/64, 32 bh, KSPLIT), block 256 = 4 independent waves x 16 q-rows.
// S^T = mfma(K, Q): lane owns q = lane&15. PV B-frags from global Vt.
__global__ __launch_bounds__(256, 4) void attn_mfma(
    const bf16* __restrict__ QP, const bf16* __restrict__ KP,
    const bf16* __restrict__ Vt, const unsigned* __restrict__ bits,
    bf16* __restrict__ Opart, float* __restrict__ Mpart,
    float* __restrict__ Lpart)
{
    __shared__ bf16 Pl[4][16][72];     // per-wave private P tile
    int tid = threadIdx.x;
    int lane = tid & 63, wv = tid >> 6;
    int g = lane >> 4, c = lane & 15;
    int bh = blockIdx.y, b = bh >> 3;
    int q0 = blockIdx.x * 64 + wv * 16;
    int sp = blockIdx.z;

    long qrow0 = (long)bh * 1024 + q0;
    long krow0 = (long)bh * 2048;
    const bf16* vtb = Vt + (long)bh * 64 * 2048;
    const unsigned* bitrow = bits + ((long)b * 1024 + q0 + c) * 64;

    bf16x8 qa[2];
#pragma unroll
    for (int hh = 0; hh < 2; hh++)
        qa[hh] = *(const bf16x8*)(QP + (qrow0 + c) * 64 + hh * 32 + g * 8);

    f32x4 o_acc[4];
#pragma unroll
    for (int ot = 0; ot < 4; ot++) o_acc[ot] = (f32x4){0.f, 0.f, 0.f, 0.f};
    float m_r = -1e30f, l_r = 0.f;

    for (int kt = 0; kt < LKK / KSPLIT / 64; kt++) {
        int k0 = sp * (LKK / KSPLIT) + kt * 64;

        // V B-frags: contiguous 16B loads from Vt (independent; issue early)
        bf16x8 vb[4][2];
#pragma unroll
        for (int ot = 0; ot < 4; ot++)
#pragma unroll
            for (int kh = 0; kh < 2; kh++)
                vb[ot][kh] = *(const bf16x8*)
                    (vtb + (long)(ot * 16 + c) * 2048 + k0 + kh * 32 + g * 8);

        // S^T = K Q^T
        f32x4 s[4];
#pragma unroll
        for (int mt = 0; mt < 4; mt++) {
            const bf16* krow = KP + (krow0 + k0 + mt * 16 + c) * 64;
            bf16x8 kb0 = *(const bf16x8*)(krow + g * 8);
            bf16x8 kb1 = *(const bf16x8*)(krow + 32 + g * 8);
            s[mt] = mfma16(kb0, qa[0], (f32x4){0.f, 0.f, 0.f, 0.f});
            s[mt] = mfma16(kb1, qa[1], s[mt]);
        }

        // mask + scale
        uint2 wp = *(const uint2*)(bitrow + (k0 >> 5));
#pragma unroll
        for (int mt = 0; mt < 4; mt++)
#pragma unroll
            for (int j = 0; j < 4; j++) {
                int kl = mt * 16 + 4 * g + j;
                unsigned wsel = (kl < 32) ? wp.x : wp.y;
                s[mt][j] = ((wsel >> (kl & 31)) & 1) ? -1e30f : s[mt][j] * 0.125f;
            }

        // online softmax: lane-local 16 + 2 shfl_xor
        float mx = -1e30f;
#pragma unroll
        for (int mt = 0; mt < 4; mt++)
            mx = fmaxf(mx, fmaxf(fmaxf(s[mt][0], s[mt][1]),
                                 fmaxf(s[mt][2], s[mt][3])));
        mx = fmaxf(mx, __shfl_xor(mx, 16, 64));
        mx = fmaxf(mx, __shfl_xor(mx, 32, 64));
        float mnew = fmaxf(m_r, mx);
        float fct = __expf(m_r - mnew);
        m_r = mnew;
        float sum = 0.f;
#pragma unroll
        for (int mt = 0; mt < 4; mt++)
#pragma unroll
            for (int j = 0; j < 4; j++) {
                float p = __expf(s[mt][j] - mnew);
                s[mt][j] = p;
                sum += p;
            }
        sum += __shfl_xor(sum, 16, 64);
        sum += __shfl_xor(sum, 32, 64);
        l_r = l_r * fct + sum;

        // P -> per-wave LDS (A-frag layout), q = c
#pragma unroll
        for (int mt = 0; mt < 4; mt++) {
            bf16x4 pk;
#pragma unroll
            for (int j = 0; j < 4; j++) pk[j] = (bf16)s[mt][j];
            *(bf16x4*)&Pl[wv][c][mt * 16 + 4 * g] = pk;
        }

        // rescale O (rows are q = 4g+j)
        float fq[4];
#pragma unroll
        for (int j = 0; j < 4; j++)
            fq[j] = __shfl(fct, (lane & 48) | (4 * g + j), 64);
#pragma unroll
        for (int ot = 0; ot < 4; ot++)
#pragma unroll
            for (int j = 0; j < 4; j++) o_acc[ot][j] *= fq[j];

        // PV
#pragma unroll
        for (int kh = 0; kh < 2; kh++) {
            bf16x8 pa = *(const bf16x8*)&Pl[wv][c][kh * 32 + g * 8];
#pragma unroll
            for (int ot = 0; ot < 4; ot++)
                o_acc[ot] = mfma16(pa, vb[ot][kh], o_acc[ot]);
        }
    }

    // write raw partials
    long ob = ((long)sp * NROWS + qrow0) * 64;
#pragma unroll
    for (int ot = 0; ot < 4; ot++)
#pragma unroll
        for (int j = 0; j < 4; j++)
            Opart[ob + (long)(4 * g + j) * 64 + ot * 16 + c] = (bf16)o_acc[ot][j];
    if (g == 0) {
        Mpart[(long)sp * NROWS + qrow0 + c] = m_r;
        Lpart[(long)sp * NROWS + qrow0 + c] = l_r;
    }
}

// ------------- combine k-split partials -------------
__global__ __launch_bounds__(256) void attn_combine(
    const bf16* __restrict__ Op, const float* __restrict__ Mp,
    const float* __restrict__ Lp, bf16* __restrict__ O)
{
    long idx = (long)blockIdx.x * 256 + threadIdx.x;
    long row = idx >> 6;
    float m0 = Mp[row], m1 = Mp[NROWS + row];
    float l0 = Lp[row], l1 = Lp[NROWS + row];
    float mm = fmaxf(m0, m1);
    float e0 = __expf(m0 - mm), e1 = __expf(m1 - mm);
    float inv = 1.f / (l0 * e0 + l1 * e1);
    float o = ((float)Op[idx] * e0 + (float)Op[(long)NROWS * 64 + idx] * e1) * inv;
    O[idx] = (bf16)o;
}

// ------------- LN(residual) -------------
__global__ __launch_bounds__(256) void ln_kernel(
    const float* __restrict__ res, const float* __restrict__ y,
    const float* __restrict__ g, const float* __restrict__ bb,
    float* __restrict__ outf, bf16* __restrict__ outb)
{
    int wave = threadIdx.x >> 6, lane = threadIdx.x & 63;
    long row = (long)blockIdx.x * 4 + wave;
    const float* rp = res + row * D_MODEL;
    const float* yp = y + row * D_MODEL;
    float v[8];
    float s = 0.f, sq = 0.f;
#pragma unroll
    for (int j = 0; j < 8; j++) {
        int col = lane + 64 * j;
        v[j] = rp[col] + yp[col];
        s += v[j]; sq += v[j] * v[j];
    }
#pragma unroll
    for (int o = 32; o > 0; o >>= 1) {
        s += __shfl_down(s, o, 64);
        sq += __shfl_down(sq, o, 64);
    }
    s = __shfl(s, 0, 64);
    sq = __shfl(sq, 0, 64);
    float mean = s * (1.f / 512.f);
    float var = sq * (1.f / 512.f) - mean * mean;
    float rstd = rsqrtf(fmaxf(var, 0.f) + 1e-5f);
    float* opf = outf + row * D_MODEL;
    bf16* opb = outb + row * D_MODEL;
#pragma unroll
    for (int j = 0; j < 8; j++) {
        int col = lane + 64 * j;
        float o = (v[j] - mean) * rstd * g[col] + bb[col];
        opf[col] = o;
        opb[col] = (bf16)o;
    }
}

extern "C" void kernel_launch(void* const* d_in, const int* in_sizes, int n_in,
                              void* d_out, int out_size, void* d_ws, size_t ws_size,
                              hipStream_t stream)
{
    const float* x    = (const float*)d_in[0];
    const float* hin  = (const float*)d_in[1];
    const int*   mask = (const int*)d_in[2];
    const float* wq   = (const float*)d_in[3];
    const float* wk   = (const float*)d_in[4];
    const float* wv   = (const float*)d_in[5];
    const float* wo   = (const float*)d_in[6];
    const float* ffw1 = (const float*)d_in[7];
    const float* ffb1 = (const float*)d_in[8];
    const float* ffw2 = (const float*)d_in[9];
    const float* ffb2 = (const float*)d_in[10];
    const float* g1   = (const float*)d_in[11];
    const float* be1  = (const float*)d_in[12];
    const float* g2   = (const float*)d_in[13];
    const float* be2  = (const float*)d_in[14];
    const float* out_wq = (const float*)d_in[15];
    const float* out_wk = (const float*)d_in[16];
    float* out = (float*)d_out;

    const long NQ = (long)BB * LQ;   // 4096
    const long NK = (long)BB * LKK;  // 8192
    const long WSZ = 512L * 512;

    // workspace layout (bytes). SH region time-shares y_f / V-plane / Opart.
    char* W = (char*)d_ws;
    float* h_f  = (float*)(W);                      // 8 MB
    char*  SH   = W + 8388608;                      // 8 MB shared region
    float* y_f  = (float*)SH;
    bf16*  v_pl = (bf16*)SH;
    bf16*  opart= (bf16*)SH;
    bf16*  h_b  = (bf16*)(W + 16777216);            // 4 MB
    bf16*  x_b  = (bf16*)(W + 20971520);            // 8 MB
    bf16*  q_b  = (bf16*)(W + 29360128);            // 4 MB
    bf16*  a_b  = (bf16*)(W + 33554432);            // 4 MB
    bf16*  k_pl = (bf16*)(W + 37748736);            // 8 MB
    bf16*  vt   = (bf16*)(W + 46137344);            // 8 MB
    bf16*  wts  = (bf16*)(W + 54525952);            // 10 MB
    bf16*  wtQ  = wts;
    bf16*  wtO  = wts + 3 * WSZ;
    bf16*  wtF1 = wts + 6 * WSZ;
    bf16*  wtF2 = wts + 9 * WSZ;
    bf16*  wtKV = wts + 12 * WSZ;                   // K0,V0,K1,V1,K2,V2,OutK
    bf16*  wtOQ = wts + 19 * WSZ;
    unsigned* mb = (unsigned*)(W + 65011712);       // 1 MB
    float* Mpart = (float*)(W + 66060288);          // 256 KB
    float* Lpart = (float*)(W + 66322432);          // 256 KB

    const long sKV = ((bf16*)SH) - k_pl;            // element offset K-plane -> V-plane

    dim3 blk(256);

    // preprocessing
    hipMemcpyAsync(h_f, hin, NQ * D_MODEL * sizeof(float),
                   hipMemcpyDeviceToDevice, stream);
    cast_kernel<<<dim3((NK * D_MODEL / 4 + 255) / 256), blk, 0, stream>>>(x, x_b, NK * D_MODEL);
    cast_kernel<<<dim3((NQ * D_MODEL / 4 + 255) / 256), blk, 0, stream>>>(hin, h_b, NQ * D_MODEL);
    dim3 gt(16, 16, 3);
    tcast_kernel<<<gt, blk, 0, stream>>>(wq, wtQ, WSZ);
    tcast_kernel<<<gt, blk, 0, stream>>>(wo, wtO, WSZ);
    tcast_kernel<<<gt, blk, 0, stream>>>(ffw1, wtF1, WSZ);
    tcast_kernel<<<gt, blk, 0, stream>>>(ffw2, wtF2, WSZ);
    tcast_kernel<<<gt, blk, 0, stream>>>(wk, wtKV, 2 * WSZ);
    tcast_kernel<<<gt, blk, 0, stream>>>(wv, wtKV + WSZ, 2 * WSZ);
    dim3 gt1(16, 16, 1);
    tcast_kernel<<<gt1, blk, 0, stream>>>(out_wk, wtKV + 6 * WSZ, 0);
    tcast_kernel<<<gt1, blk, 0, stream>>>(out_wq, wtOQ, 0);
    maskbits_kernel<<<dim3(32768), blk, 0, stream>>>(mask, mb);

    dim3 gq(8, 32, 1);           // 4096 x 512 (128x64)
    dim3 gkv(4, 64, 2);          // 8192 x 512, z = {K,V} (128x128)
    dim3 gvt(32, 32);
    dim3 ga(LQ / 64, 32, KSPLIT);
    dim3 gc(NROWS * 64 / 256);

    for (int i = 0; i < NL; i++) {
        mfma_gemm<0,0,1><<<gq, blk, 0, stream>>>(h_b, wtQ + i * WSZ, nullptr, q_b,
            512, 512, 1.f, 0, 0, 0);
        mfma_gemm128<1><<<gkv, blk, 0, stream>>>(x_b, wtKV + 2 * i * WSZ, k_pl,
            512, 512, 1.f, 0, WSZ, sKV);
        vtrans_kernel<<<gvt, blk, 0, stream>>>(v_pl, vt);

        attn_mfma<<<ga, blk, 0, stream>>>(q_b, k_pl, vt, mb, opart, Mpart, Lpart);
        attn_combine<<<gc, blk, 0, stream>>>(opart, Mpart, Lpart, a_b);

        mfma_gemm<0,0,0><<<gq, blk, 0, stream>>>(a_b, wtO + i * WSZ, nullptr, y_f,
            512, 512, 1.f, 0, 0, 0);
        ln_kernel<<<dim3(NQ / 4), blk, 0, stream>>>(h_f, y_f,
            g1 + i * D_MODEL, be1 + i * D_MODEL, h_f, h_b);

        mfma_gemm<1,1,1><<<gq, blk, 0, stream>>>(h_b, wtF1 + i * WSZ,
            ffb1 + i * D_MODEL, q_b, 512, 512, 1.f, 0, 0, 0);
        mfma_gemm<1,0,0><<<gq, blk, 0, stream>>>(q_b, wtF2 + i * WSZ,
            ffb2 + i * D_MODEL, y_f, 512, 512, 1.f, 0, 0, 0);
        ln_kernel<<<dim3(NQ / 4), blk, 0, stream>>>(h_f, y_f,
            g2 + i * D_MODEL, be2 + i * D_MODEL, h_f, h_b);
    }

    // final scores
    mfma_gemm<0,0,1><<<gq, blk, 0, stream>>>(h_b, wtOQ, nullptr, q_b,
        512, 512, 1.f, 0, 0, 0);
    dim3 gkf(4, 64, 1);
    mfma_gemm128<1><<<gkf, blk, 0, stream>>>(x_b, wtKV + 6 * WSZ, k_pl,
        512, 512, 1.f, 0, 0, 0);
    dim3 gf(LKK / 128, LQ / 128, BB);
    mfma_gemm128<0><<<gf, blk, 0, stream>>>(q_b, k_pl, out,
        LKK, 512, 0.04419417382415922f,
        (long)LQ * 512, (long)LKK * 512, (long)LQ * LKK);
}

// Round 5
// 581.730 us; speedup vs baseline: 1.2544x; 1.2544x over previous
//
#include <hip/hip_runtime.h>
#include <math.h>

// bf16-MFMA decoder, round 5.
// Attention: XCD-swizzled grid (per-XCD L2-resident K/V), K tile staged in LDS
// (double-buffered, XOR-swizzled via pre-swizzled global src, one barrier/tile),
// V frags from global Vt, defer-max online softmax (THR=8), KSPLIT=2 + combine.

#define D_MODEL 512
#define LQ 1024
#define LKK 2048
#define BB 4
#define NL 3
#define KSPLIT 2
#define NROWS 32768   // packed q-rows total = B*8*1024

typedef __bf16 bf16;
typedef __bf16 bf16x8 __attribute__((ext_vector_type(8)));
typedef __bf16 bf16x4 __attribute__((ext_vector_type(4)));
typedef float f32x4 __attribute__((ext_vector_type(4)));

__device__ inline f32x4 mfma16(bf16x8 a, bf16x8 b, f32x4 c) {
    return __builtin_amdgcn_mfma_f32_16x16x32_bf16(a, b, c, 0, 0, 0);
}

__device__ inline void gload16(const void* g, void* l) {
    __builtin_amdgcn_global_load_lds(
        (const __attribute__((address_space(1))) void*)g,
        (__attribute__((address_space(3))) void*)l, 16, 0, 0);
}

// ---------------- cast fp32 -> bf16 ----------------
__global__ __launch_bounds__(256) void cast_kernel(
    const float* __restrict__ in, bf16* __restrict__ out, long n)
{
    long i4 = ((long)blockIdx.x * 256 + threadIdx.x) * 4;
    if (i4 >= n) return;
    float4 v = *(const float4*)(in + i4);
    bf16x4 o;
    o[0] = (bf16)v.x; o[1] = (bf16)v.y; o[2] = (bf16)v.z; o[3] = (bf16)v.w;
    *(bf16x4*)(out + i4) = o;
}

// ------- transpose-cast W[512][512] fp32 -> bf16 NT, strided dst per z -------
__global__ __launch_bounds__(256) void tcast_kernel(
    const float* __restrict__ in, bf16* __restrict__ out, long dstride)
{
    __shared__ float t[32][33];
    const float* ip = in + (long)blockIdx.z * 262144;
    bf16* op = out + (long)blockIdx.z * dstride;
    int tx = threadIdx.x & 31, ty = threadIdx.x >> 5;
    int x0 = blockIdx.x * 32, y0 = blockIdx.y * 32;
#pragma unroll
    for (int i = 0; i < 4; i++)
        t[ty + 8 * i][tx] = ip[(long)(y0 + ty + 8 * i) * 512 + x0 + tx];
    __syncthreads();
#pragma unroll
    for (int i = 0; i < 4; i++)
        op[(long)(x0 + ty + 8 * i) * 512 + y0 + tx] = (bf16)t[tx][ty + 8 * i];
}

// ------------- mask (int32) -> packed bits -------------
__global__ __launch_bounds__(256) void maskbits_kernel(
    const int* __restrict__ m, unsigned* __restrict__ bits)
{
    long i = (long)blockIdx.x * 256 + threadIdx.x;
    int v = m[i] != 0;
    unsigned long long bal = __ballot(v);
    int lane = threadIdx.x & 63;
    if (lane == 0) bits[i >> 5] = (unsigned)bal;
    else if (lane == 32) bits[i >> 5] = (unsigned)(bal >> 32);
}

// ------------- V transpose: v[(bh)*2048+p][64] -> vt[(bh)*64+d][2048] -------------
__global__ __launch_bounds__(256) void vtrans_kernel(
    const bf16* __restrict__ v, bf16* __restrict__ vt)
{
    __shared__ bf16 t[64][72];
    int bh = blockIdx.y;
    int p0 = blockIdx.x * 64;
    const bf16* vb = v + ((long)bh * 2048 + p0) * 64;
    bf16* vtb = vt + (long)bh * 64 * 2048;
    int tid = threadIdx.x;
#pragma unroll
    for (int it = 0; it < 2; it++) {
        int r = it * 32 + (tid >> 3);
        int c8 = (tid & 7) * 8;
        bf16x8 vv = *(const bf16x8*)(vb + (long)r * 64 + c8);
        *(bf16x8*)&t[r][c8] = vv;
    }
    __syncthreads();
#pragma unroll
    for (int it = 0; it < 2; it++) {
        int d = it * 32 + (tid >> 3);
        int p8 = (tid & 7) * 8;
        bf16x8 ov;
#pragma unroll
        for (int j = 0; j < 8; j++) ov[j] = t[p8 + j][d];
        *(bf16x8*)(vtb + (long)d * 2048 + p0 + p8) = ov;
    }
}

// ------------- 128x64 MFMA GEMM (projections) -------------
template<int BIAS, int RELU, int OUT_BF16>
__global__ __launch_bounds__(256) void mfma_gemm(
    const bf16* __restrict__ A, const bf16* __restrict__ Bt,
    const float* __restrict__ bias, void* __restrict__ Cv,
    int N, int K, float scale, long sA, long sB, long sC)
{
    __shared__ bf16 As[128][32];
    __shared__ bf16 Bs[64][32];
    int tid = threadIdx.x;
    int lane = tid & 63, w = tid >> 6;
    int wr = w >> 1, wc = w & 1;
    int g = lane >> 4, c = lane & 15;
    long z = blockIdx.z;
    const bf16* Ab = A + z * sA;
    const bf16* Bb = Bt + z * sB;
    long row0 = (long)blockIdx.y * 128;
    int n0 = blockIdx.x * 64;

    f32x4 acc[4][2];
#pragma unroll
    for (int m = 0; m < 4; m++)
#pragma unroll
        for (int n = 0; n < 2; n++) acc[m][n] = (f32x4){0.f, 0.f, 0.f, 0.f};

    for (int k0 = 0; k0 < K; k0 += 32) {
        __syncthreads();
        const bf16* ga = Ab + (row0 + w * 32 + (lane >> 2)) * K + k0 + (lane & 3) * 8;
        gload16(ga, &As[w * 32][0]);
        gload16(ga + (long)16 * K, &As[w * 32 + 16][0]);
        const bf16* gb = Bb + (long)(n0 + w * 16 + (lane >> 2)) * K + k0 + (lane & 3) * 8;
        gload16(gb, &Bs[w * 16][0]);
        __syncthreads();
        bf16x8 af[4], bfr[2];
#pragma unroll
        for (int m = 0; m < 4; m++)
            af[m] = *(const bf16x8*)&As[wr * 64 + m * 16 + c][g * 8];
#pragma unroll
        for (int n = 0; n < 2; n++)
            bfr[n] = *(const bf16x8*)&Bs[wc * 32 + n * 16 + c][g * 8];
#pragma unroll
        for (int m = 0; m < 4; m++)
#pragma unroll
            for (int n = 0; n < 2; n++)
                acc[m][n] = mfma16(af[m], bfr[n], acc[m][n]);
    }

    float bv[2] = {0.f, 0.f};
    if (BIAS) {
#pragma unroll
        for (int n = 0; n < 2; n++) bv[n] = bias[n0 + wc * 32 + n * 16 + c];
    }
    float* Cf = (float*)Cv + z * sC;
    bf16* Cb = (bf16*)Cv + z * sC;
#pragma unroll
    for (int m = 0; m < 4; m++)
#pragma unroll
        for (int n = 0; n < 2; n++)
#pragma unroll
            for (int j = 0; j < 4; j++) {
                long row = row0 + wr * 64 + m * 16 + g * 4 + j;
                int col = n0 + wc * 32 + n * 16 + c;
                float v = acc[m][n][j] * scale;
                if (BIAS) v += bv[n];
                if (RELU) v = fmaxf(v, 0.f);
                if (OUT_BF16) Cb[row * N + col] = (bf16)v;
                else Cf[row * N + col] = v;
            }
}

// ------------- 128x128 MFMA GEMM (big GEMMs) -------------
template<int OUT_BF16>
__global__ __launch_bounds__(256) void mfma_gemm128(
    const bf16* __restrict__ A, const bf16* __restrict__ Bt,
    void* __restrict__ Cv, int N, int K, float scale,
    long sA, long sB, long sC)
{
    __shared__ bf16 As[128][32];
    __shared__ bf16 Bs[128][32];
    int tid = threadIdx.x;
    int lane = tid & 63, w = tid >> 6;
    int wr = w >> 1, wc = w & 1;
    int g = lane >> 4, c = lane & 15;
    long z = blockIdx.z;
    const bf16* Ab = A + z * sA;
    const bf16* Bb = Bt + z * sB;
    long row0 = (long)blockIdx.y * 128;
    int n0 = blockIdx.x * 128;

    f32x4 acc[4][4];
#pragma unroll
    for (int m = 0; m < 4; m++)
#pragma unroll
        for (int n = 0; n < 4; n++) acc[m][n] = (f32x4){0.f, 0.f, 0.f, 0.f};

    for (int k0 = 0; k0 < K; k0 += 32) {
        __syncthreads();
        const bf16* ga = Ab + (row0 + w * 16 + (lane >> 2)) * K + k0 + (lane & 3) * 8;
        gload16(ga, &As[w * 16][0]);
        gload16(ga + (long)64 * K, &As[w * 16 + 64][0]);
        const bf16* gb = Bb + (long)(n0 + w * 16 + (lane >> 2)) * K + k0 + (lane & 3) * 8;
        gload16(gb, &Bs[w * 16][0]);
        gload16(gb + (long)64 * K, &Bs[w * 16 + 64][0]);
        __syncthreads();
        bf16x8 af[4], bfr[4];
#pragma unroll
        for (int m = 0; m < 4; m++)
            af[m] = *(const bf16x8*)&As[wr * 64 + m * 16 + c][g * 8];
#pragma unroll
        for (int n = 0; n < 4; n++)
            bfr[n] = *(const bf16x8*)&Bs[wc * 64 + n * 16 + c][g * 8];
#pragma unroll
        for (int m = 0; m < 4; m++)
#pragma unroll
            for (int n = 0; n < 4; n++)
                acc[m][n] = mfma16(af[m], bfr[n], acc[m][n]);
    }

    float* Cf = (float*)Cv + z * sC;
    bf16* Cb = (bf16*)Cv + z * sC;
#pragma unroll
    for (int m = 0; m < 4; m++)
#pragma unroll
        for (int n = 0; n < 4; n++)
#pragma unroll
            for (int j = 0; j < 4; j++) {
                long row = row0 + wr * 64 + m * 16 + g * 4 + j;
                int col = n0 + wc * 64 + n * 16 + c;
                float v = acc[m][n][j] * scale;
                if (OUT_BF16) Cb[row * N + col] = (bf16)v;
                else Cf[row * N + col] = v;
            }
}

// ------------- MFMA flash attention (XCD-swizzled, K in LDS dbuf) -------------
// Flat grid 1024 blocks = (16 qb, 32 bh, 2 sp), XCD k owns bh 4k..4k+3.
// Block = 4 waves x 16 q-rows. K tile (64 keys x 64 d) staged in LDS,
// double-buffered, XOR-swizzled (pre-swizzled global src). One barrier/tile.
__global__ __launch_bounds__(256, 4) void attn_mfma(
    const bf16* __restrict__ QP, const bf16* __restrict__ KP,
    const bf16* __restrict__ Vt, const unsigned* __restrict__ bits,
    bf16* __restrict__ Opart, float* __restrict__ Mpart,
    float* __restrict__ Lpart)
{
    __shared__ bf16 Kls[2][4096];      // 2 x (64 keys x 64 d), swizzled
    __shared__ bf16 Pl[4][16][72];     // per-wave P tile [q=c][key]

    int tid = threadIdx.x;
    int lane = tid & 63, wv = tid >> 6;
    int g = lane >> 4, c = lane & 15;

    int flat = blockIdx.x;
    int logical = (flat & 7) * 128 + (flat >> 3);   // XCD-chunked
    int bh = logical >> 5;
    int rr = logical & 31;
    int sp = rr >> 4;
    int q0 = (rr & 15) * 64 + wv * 16;
    int b = bh >> 3;

    long qrow0 = (long)bh * 1024 + q0;
    long krow0 = (long)bh * 2048 + (long)sp * 1024;
    const bf16* vtb = Vt + (long)bh * 131072 + (long)sp * 1024;
    const unsigned* bitrow = bits + ((long)b * 1024 + q0 + c) * 64 + sp * 32;

    // staging geometry: lane l covers row (l>>3), col bytes swizzled by row&7
    int lr = lane >> 3, lc = lane & 7;
    int scol = (lc ^ lr) * 8;                       // pre-swizzled src col (elems)

    bf16x8 qa[2];
#pragma unroll
    for (int hh = 0; hh < 2; hh++)
        qa[hh] = *(const bf16x8*)(QP + (qrow0 + c) * 64 + hh * 32 + g * 8);

    f32x4 o_acc[4];
#pragma unroll
    for (int ot = 0; ot < 4; ot++) o_acc[ot] = (f32x4){0.f, 0.f, 0.f, 0.f};
    float m_r = -1e30f, l_r = 0.f;

    // prologue: stage tile 0
    {
        const bf16* s0 = KP + (krow0 + wv * 16 + lr) * 64 + scol;
        gload16(s0, &Kls[0][(wv * 16) * 64]);
        gload16(s0 + 8 * 64, &Kls[0][(wv * 16 + 8) * 64]);
    }
    __syncthreads();

    const int NT = LKK / KSPLIT / 64;   // 16
    for (int kt = 0; kt < NT; kt++) {
        int cur = kt & 1;
        // prefetch next K tile into other buffer
        if (kt + 1 < NT) {
            const bf16* s0 = KP + (krow0 + (long)(kt + 1) * 64 + wv * 16 + lr) * 64 + scol;
            gload16(s0, &Kls[cur ^ 1][(wv * 16) * 64]);
            gload16(s0 + 8 * 64, &Kls[cur ^ 1][(wv * 16 + 8) * 64]);
        }
        int k0 = kt * 64;

        // mask bits for this tile (q = c)
        uint2 wp = *(const uint2*)(bitrow + kt * 2);

        // V B-frags from global Vt (L2-resident; needed only at PV)
        bf16x8 vb[4][2];
#pragma unroll
        for (int ot = 0; ot < 4; ot++)
#pragma unroll
            for (int kh = 0; kh < 2; kh++)
                vb[ot][kh] = *(const bf16x8*)
                    (vtb + (long)(ot * 16 + c) * 2048 + k0 + kh * 32 + g * 8);

        // S^T = K Q^T from LDS (swizzled read; 2-way conflicts = free)
        const char* kls = (const char*)&Kls[cur][0];
        f32x4 s[4];
#pragma unroll
        for (int mt = 0; mt < 4; mt++) {
            bf16x8 ka0 = *(const bf16x8*)(kls + (mt * 16 + c) * 128 + ((g ^ (c & 7)) << 4));
            bf16x8 ka1 = *(const bf16x8*)(kls + (mt * 16 + c) * 128 + (((4 + g) ^ (c & 7)) << 4));
            s[mt] = mfma16(ka0, qa[0], (f32x4){0.f, 0.f, 0.f, 0.f});
            s[mt] = mfma16(ka1, qa[1], s[mt]);
        }

        // mask + scale (lane's q = c)
#pragma unroll
        for (int mt = 0; mt < 4; mt++)
#pragma unroll
            for (int j = 0; j < 4; j++) {
                int kl = mt * 16 + 4 * g + j;
                unsigned wsel = (kl < 32) ? wp.x : wp.y;
                s[mt][j] = ((wsel >> (kl & 31)) & 1) ? -1e30f : s[mt][j] * 0.125f;
            }

        // online softmax with defer-max (THR=8)
        float mx = -1e30f;
#pragma unroll
        for (int mt = 0; mt < 4; mt++)
            mx = fmaxf(mx, fmaxf(fmaxf(s[mt][0], s[mt][1]),
                                 fmaxf(s[mt][2], s[mt][3])));
        mx = fmaxf(mx, __shfl_xor(mx, 16, 64));
        mx = fmaxf(mx, __shfl_xor(mx, 32, 64));

        float fct = 1.f;
        if (__any(mx > m_r + 8.f)) {
            float mnew = fmaxf(m_r, mx);
            fct = __expf(m_r - mnew);
            m_r = mnew;
            float fq[4];
#pragma unroll
            for (int j = 0; j < 4; j++)
                fq[j] = __shfl(fct, (lane & 48) | (4 * g + j), 64);
#pragma unroll
            for (int ot = 0; ot < 4; ot++)
#pragma unroll
                for (int j = 0; j < 4; j++) o_acc[ot][j] *= fq[j];
        }

        float sum = 0.f;
#pragma unroll
        for (int mt = 0; mt < 4; mt++)
#pragma unroll
            for (int j = 0; j < 4; j++) {
                float p = __expf(s[mt][j] - m_r);
                s[mt][j] = p;
                sum += p;
            }
        sum += __shfl_xor(sum, 16, 64);
        sum += __shfl_xor(sum, 32, 64);
        l_r = l_r * fct + sum;

        // P -> per-wave LDS (A-frag layout), q = c
#pragma unroll
        for (int mt = 0; mt < 4; mt++) {
            bf16x4 pk;
#pragma unroll
            for (int j = 0; j < 4; j++) pk[j] = (bf16)s[mt][j];
            *(bf16x4*)&Pl[wv][c][mt * 16 + 4 * g] = pk;
        }

        // PV
#pragma unroll
        for (int kh = 0; kh < 2; kh++) {
            bf16x8 pa = *(const bf16x8*)&Pl[wv][c][kh * 32 + g * 8];
#pragma unroll
            for (int ot = 0; ot < 4; ot++)
                o_acc[ot] = mfma16(pa, vb[ot][kh], o_acc[ot]);
        }
        __syncthreads();   // next-tile stage done + safe to overwrite buffers
    }

    // write raw partials
    long ob = ((long)sp * NROWS + qrow0) * 64;
#pragma unroll
    for (int ot = 0; ot < 4; ot++)
#pragma unroll
        for (int j = 0; j < 4; j++)
            Opart[ob + (long)(4 * g + j) * 64 + ot * 16 + c] = (bf16)o_acc[ot][j];
    if (g == 0) {
        Mpart[(long)sp * NROWS + qrow0 + c] = m_r;
        Lpart[(long)sp * NROWS + qrow0 + c] = l_r;
    }
}

// ------------- combine k-split partials -------------
__global__ __launch_bounds__(256) void attn_combine(
    const bf16* __restrict__ Op, const float* __restrict__ Mp,
    const float* __restrict__ Lp, bf16* __restrict__ O)
{
    long idx = (long)blockIdx.x * 256 + threadIdx.x;
    long row = idx >> 6;
    float m0 = Mp[row], m1 = Mp[NROWS + row];
    float l0 = Lp[row], l1 = Lp[NROWS + row];
    float mm = fmaxf(m0, m1);
    float e0 = __expf(m0 - mm), e1 = __expf(m1 - mm);
    float inv = 1.f / (l0 * e0 + l1 * e1);
    float o = ((float)Op[idx] * e0 + (float)Op[(long)NROWS * 64 + idx] * e1) * inv;
    O[idx] = (bf16)o;
}

// ------------- LN(residual) -------------
__global__ __launch_bounds__(256) void ln_kernel(
    const float* __restrict__ res, const float* __restrict__ y,
    const float* __restrict__ g, const float* __restrict__ bb,
    float* __restrict__ outf, bf16* __restrict__ outb)
{
    int wave = threadIdx.x >> 6, lane = threadIdx.x & 63;
    long row = (long)blockIdx.x * 4 + wave;
    const float* rp = res + row * D_MODEL;
    const float* yp = y + row * D_MODEL;
    float v[8];
    float s = 0.f, sq = 0.f;
#pragma unroll
    for (int j = 0; j < 8; j++) {
        int col = lane + 64 * j;
        v[j] = rp[col] + yp[col];
        s += v[j]; sq += v[j] * v[j];
    }
#pragma unroll
    for (int o = 32; o > 0; o >>= 1) {
        s += __shfl_down(s, o, 64);
        sq += __shfl_down(sq, o, 64);
    }
    s = __shfl(s, 0, 64);
    sq = __shfl(sq, 0, 64);
    float mean = s * (1.f / 512.f);
    float var = sq * (1.f / 512.f) - mean * mean;
    float rstd = rsqrtf(fmaxf(var, 0.f) + 1e-5f);
    float* opf = outf + row * D_MODEL;
    bf16* opb = outb + row * D_MODEL;
#pragma unroll
    for (int j = 0; j < 8; j++) {
        int col = lane + 64 * j;
        float o = (v[j] - mean) * rstd * g[col] + bb[col];
        opf[col] = o;
        opb[col] = (bf16)o;
    }
}

extern "C" void kernel_launch(void* const* d_in, const int* in_sizes, int n_in,
                              void* d_out, int out_size, void* d_ws, size_t ws_size,
                              hipStream_t stream)
{
    const float* x    = (const float*)d_in[0];
    const float* hin  = (const float*)d_in[1];
    const int*   mask = (const int*)d_in[2];
    const float* wq   = (const float*)d_in[3];
    const float* wk   = (const float*)d_in[4];
    const float* wv   = (const float*)d_in[5];
    const float* wo   = (const float*)d_in[6];
    const float* ffw1 = (const float*)d_in[7];
    const float* ffb1 = (const float*)d_in[8];
    const float* ffw2 = (const float*)d_in[9];
    const float* ffb2 = (const float*)d_in[10];
    const float* g1   = (const float*)d_in[11];
    const float* be1  = (const float*)d_in[12];
    const float* g2   = (const float*)d_in[13];
    const float* be2  = (const float*)d_in[14];
    const float* out_wq = (const float*)d_in[15];
    const float* out_wk = (const float*)d_in[16];
    float* out = (float*)d_out;

    const long NQ = (long)BB * LQ;   // 4096
    const long NK = (long)BB * LKK;  // 8192
    const long WSZ = 512L * 512;

    // workspace layout (bytes). SH region time-shares y_f / V-plane.
    char* W = (char*)d_ws;
    float* h_f  = (float*)(W);                      // 8 MB
    char*  SH   = W + 8388608;                      // 8 MB shared region
    float* y_f  = (float*)SH;
    bf16*  v_pl = (bf16*)SH;
    bf16*  opart= (bf16*)SH;
    bf16*  h_b  = (bf16*)(W + 16777216);            // 4 MB
    bf16*  x_b  = (bf16*)(W + 20971520);            // 8 MB
    bf16*  q_b  = (bf16*)(W + 29360128);            // 4 MB
    bf16*  a_b  = (bf16*)(W + 33554432);            // 4 MB
    bf16*  k_pl = (bf16*)(W + 37748736);            // 8 MB
    bf16*  vt   = (bf16*)(W + 46137344);            // 8 MB
    bf16*  wts  = (bf16*)(W + 54525952);            // 10 MB
    bf16*  wtQ  = wts;
    bf16*  wtO  = wts + 3 * WSZ;
    bf16*  wtF1 = wts + 6 * WSZ;
    bf16*  wtF2 = wts + 9 * WSZ;
    bf16*  wtKV = wts + 12 * WSZ;                   // K0,V0,K1,V1,K2,V2,OutK
    bf16*  wtOQ = wts + 19 * WSZ;
    unsigned* mb = (unsigned*)(W + 65011712);       // 1 MB
    float* Mpart = (float*)(W + 66060288);          // 256 KB
    float* Lpart = (float*)(W + 66322432);          // 256 KB

    const long sKV = ((bf16*)SH) - k_pl;            // element offset K-plane -> V-plane

    dim3 blk(256);

    // preprocessing
    hipMemcpyAsync(h_f, hin, NQ * D_MODEL * sizeof(float),
                   hipMemcpyDeviceToDevice, stream);
    cast_kernel<<<dim3((NK * D_MODEL / 4 + 255) / 256), blk, 0, stream>>>(x, x_b, NK * D_MODEL);
    cast_kernel<<<dim3((NQ * D_MODEL / 4 + 255) / 256), blk, 0, stream>>>(hin, h_b, NQ * D_MODEL);
    dim3 gt(16, 16, 3);
    tcast_kernel<<<gt, blk, 0, stream>>>(wq, wtQ, WSZ);
    tcast_kernel<<<gt, blk, 0, stream>>>(wo, wtO, WSZ);
    tcast_kernel<<<gt, blk, 0, stream>>>(ffw1, wtF1, WSZ);
    tcast_kernel<<<gt, blk, 0, stream>>>(ffw2, wtF2, WSZ);
    tcast_kernel<<<gt, blk, 0, stream>>>(wk, wtKV, 2 * WSZ);
    tcast_kernel<<<gt, blk, 0, stream>>>(wv, wtKV + WSZ, 2 * WSZ);
    dim3 gt1(16, 16, 1);
    tcast_kernel<<<gt1, blk, 0, stream>>>(out_wk, wtKV + 6 * WSZ, 0);
    tcast_kernel<<<gt1, blk, 0, stream>>>(out_wq, wtOQ, 0);
    maskbits_kernel<<<dim3(32768), blk, 0, stream>>>(mask, mb);

    dim3 gq(8, 32, 1);           // 4096 x 512 (128x64)
    dim3 gkv(4, 64, 2);          // 8192 x 512, z = {K,V} (128x128)
    dim3 gvt(32, 32);
    dim3 ga(1024);               // flat, XCD-swizzled inside
    dim3 gc(NROWS * 64 / 256);

    for (int i = 0; i < NL; i++) {
        mfma_gemm<0,0,1><<<gq, blk, 0, stream>>>(h_b, wtQ + i * WSZ, nullptr, q_b,
            512, 512, 1.f, 0, 0, 0);
        mfma_gemm128<1><<<gkv, blk, 0, stream>>>(x_b, wtKV + 2 * i * WSZ, k_pl,
            512, 512, 1.f, 0, WSZ, sKV);
        vtrans_kernel<<<gvt, blk, 0, stream>>>(v_pl, vt);

        attn_mfma<<<ga, blk, 0, stream>>>(q_b, k_pl, vt, mb, opart, Mpart, Lpart);
        attn_combine<<<gc, blk, 0, stream>>>(opart, Mpart, Lpart, a_b);

        mfma_gemm<0,0,0><<<gq, blk, 0, stream>>>(a_b, wtO + i * WSZ, nullptr, y_f,
            512, 512, 1.f, 0, 0, 0);
        ln_kernel<<<dim3(NQ / 4), blk, 0, stream>>>(h_f, y_f,
            g1 + i * D_MODEL, be1 + i * D_MODEL, h_f, h_b);

        mfma_gemm<1,1,1><<<gq, blk, 0, stream>>>(h_b, wtF1 + i * WSZ,
            ffb1 + i * D_MODEL, q_b, 512, 512, 1.f, 0, 0, 0);
        mfma_gemm<1,0,0><<<gq, blk, 0, stream>>>(q_b, wtF2 + i * WSZ,
            ffb2 + i * D_MODEL, y_f, 512, 512, 1.f, 0, 0, 0);
        ln_kernel<<<dim3(NQ / 4), blk, 0, stream>>>(h_f, y_f,
            g2 + i * D_MODEL, be2 + i * D_MODEL, h_f, h_b);
    }

    // final scores
    mfma_gemm<0,0,1><<<gq, blk, 0, stream>>>(h_b, wtOQ, nullptr, q_b,
        512, 512, 1.f, 0, 0, 0);
    dim3 gkf(4, 64, 1);
    mfma_gemm128<1><<<gkf, blk, 0, stream>>>(x_b, wtKV + 6 * WSZ, k_pl,
        512, 512, 1.f, 0, 0, 0);
    dim3 gf(LKK / 128, LQ / 128, BB);
    mfma_gemm128<0><<<gf, blk, 0, stream>>>(q_b, k_pl, out,
        LKK, 512, 0.04419417382415922f,
        (long)LQ * 512, (long)LKK * 512, (long)LQ * LKK);
}

// Round 6
// 475.287 us; speedup vs baseline: 1.5353x; 1.2240x over previous
//
#include <hip/hip_runtime.h>
#include <math.h>

// bf16-MFMA decoder, round 6.
// Attention: K AND V tiles staged in LDS (double-buffered global_load_lds,
// pre-swizzled source XOR layout), XCD-swizzled grid, Pl XOR-swizzled to fit
// 40KB LDS = 4 blocks/CU, mask-word prefetch, defer-max softmax, KSPLIT=2.

#define D_MODEL 512
#define LQ 1024
#define LKK 2048
#define BB 4
#define NL 3
#define KSPLIT 2
#define NROWS 32768   // packed q-rows total = B*8*1024

typedef __bf16 bf16;
typedef __bf16 bf16x8 __attribute__((ext_vector_type(8)));
typedef __bf16 bf16x4 __attribute__((ext_vector_type(4)));
typedef float f32x4 __attribute__((ext_vector_type(4)));

__device__ inline f32x4 mfma16(bf16x8 a, bf16x8 b, f32x4 c) {
    return __builtin_amdgcn_mfma_f32_16x16x32_bf16(a, b, c, 0, 0, 0);
}

__device__ inline void gload16(const void* g, void* l) {
    __builtin_amdgcn_global_load_lds(
        (const __attribute__((address_space(1))) void*)g,
        (__attribute__((address_space(3))) void*)l, 16, 0, 0);
}

// ---------------- cast fp32 -> bf16 ----------------
__global__ __launch_bounds__(256) void cast_kernel(
    const float* __restrict__ in, bf16* __restrict__ out, long n)
{
    long i4 = ((long)blockIdx.x * 256 + threadIdx.x) * 4;
    if (i4 >= n) return;
    float4 v = *(const float4*)(in + i4);
    bf16x4 o;
    o[0] = (bf16)v.x; o[1] = (bf16)v.y; o[2] = (bf16)v.z; o[3] = (bf16)v.w;
    *(bf16x4*)(out + i4) = o;
}

// ------- transpose-cast W[512][512] fp32 -> bf16 NT, strided dst per z -------
__global__ __launch_bounds__(256) void tcast_kernel(
    const float* __restrict__ in, bf16* __restrict__ out, long dstride)
{
    __shared__ float t[32][33];
    const float* ip = in + (long)blockIdx.z * 262144;
    bf16* op = out + (long)blockIdx.z * dstride;
    int tx = threadIdx.x & 31, ty = threadIdx.x >> 5;
    int x0 = blockIdx.x * 32, y0 = blockIdx.y * 32;
#pragma unroll
    for (int i = 0; i < 4; i++)
        t[ty + 8 * i][tx] = ip[(long)(y0 + ty + 8 * i) * 512 + x0 + tx];
    __syncthreads();
#pragma unroll
    for (int i = 0; i < 4; i++)
        op[(long)(x0 + ty + 8 * i) * 512 + y0 + tx] = (bf16)t[tx][ty + 8 * i];
}

// ------------- mask (int32) -> packed bits -------------
__global__ __launch_bounds__(256) void maskbits_kernel(
    const int* __restrict__ m, unsigned* __restrict__ bits)
{
    long i = (long)blockIdx.x * 256 + threadIdx.x;
    int v = m[i] != 0;
    unsigned long long bal = __ballot(v);
    int lane = threadIdx.x & 63;
    if (lane == 0) bits[i >> 5] = (unsigned)bal;
    else if (lane == 32) bits[i >> 5] = (unsigned)(bal >> 32);
}

// ------------- V transpose: v[(bh)*2048+p][64] -> vt[(bh)*64+d][2048] -------------
__global__ __launch_bounds__(256) void vtrans_kernel(
    const bf16* __restrict__ v, bf16* __restrict__ vt)
{
    __shared__ bf16 t[64][72];
    int bh = blockIdx.y;
    int p0 = blockIdx.x * 64;
    const bf16* vb = v + ((long)bh * 2048 + p0) * 64;
    bf16* vtb = vt + (long)bh * 64 * 2048;
    int tid = threadIdx.x;
#pragma unroll
    for (int it = 0; it < 2; it++) {
        int r = it * 32 + (tid >> 3);
        int c8 = (tid & 7) * 8;
        bf16x8 vv = *(const bf16x8*)(vb + (long)r * 64 + c8);
        *(bf16x8*)&t[r][c8] = vv;
    }
    __syncthreads();
#pragma unroll
    for (int it = 0; it < 2; it++) {
        int d = it * 32 + (tid >> 3);
        int p8 = (tid & 7) * 8;
        bf16x8 ov;
#pragma unroll
        for (int j = 0; j < 8; j++) ov[j] = t[p8 + j][d];
        *(bf16x8*)(vtb + (long)d * 2048 + p0 + p8) = ov;
    }
}

// ------------- 128x64 MFMA GEMM (projections) -------------
template<int BIAS, int RELU, int OUT_BF16>
__global__ __launch_bounds__(256) void mfma_gemm(
    const bf16* __restrict__ A, const bf16* __restrict__ Bt,
    const float* __restrict__ bias, void* __restrict__ Cv,
    int N, int K, float scale, long sA, long sB, long sC)
{
    __shared__ bf16 As[128][32];
    __shared__ bf16 Bs[64][32];
    int tid = threadIdx.x;
    int lane = tid & 63, w = tid >> 6;
    int wr = w >> 1, wc = w & 1;
    int g = lane >> 4, c = lane & 15;
    long z = blockIdx.z;
    const bf16* Ab = A + z * sA;
    const bf16* Bb = Bt + z * sB;
    long row0 = (long)blockIdx.y * 128;
    int n0 = blockIdx.x * 64;

    f32x4 acc[4][2];
#pragma unroll
    for (int m = 0; m < 4; m++)
#pragma unroll
        for (int n = 0; n < 2; n++) acc[m][n] = (f32x4){0.f, 0.f, 0.f, 0.f};

    for (int k0 = 0; k0 < K; k0 += 32) {
        __syncthreads();
        const bf16* ga = Ab + (row0 + w * 32 + (lane >> 2)) * K + k0 + (lane & 3) * 8;
        gload16(ga, &As[w * 32][0]);
        gload16(ga + (long)16 * K, &As[w * 32 + 16][0]);
        const bf16* gb = Bb + (long)(n0 + w * 16 + (lane >> 2)) * K + k0 + (lane & 3) * 8;
        gload16(gb, &Bs[w * 16][0]);
        __syncthreads();
        bf16x8 af[4], bfr[2];
#pragma unroll
        for (int m = 0; m < 4; m++)
            af[m] = *(const bf16x8*)&As[wr * 64 + m * 16 + c][g * 8];
#pragma unroll
        for (int n = 0; n < 2; n++)
            bfr[n] = *(const bf16x8*)&Bs[wc * 32 + n * 16 + c][g * 8];
#pragma unroll
        for (int m = 0; m < 4; m++)
#pragma unroll
            for (int n = 0; n < 2; n++)
                acc[m][n] = mfma16(af[m], bfr[n], acc[m][n]);
    }

    float bv[2] = {0.f, 0.f};
    if (BIAS) {
#pragma unroll
        for (int n = 0; n < 2; n++) bv[n] = bias[n0 + wc * 32 + n * 16 + c];
    }
    float* Cf = (float*)Cv + z * sC;
    bf16* Cb = (bf16*)Cv + z * sC;
#pragma unroll
    for (int m = 0; m < 4; m++)
#pragma unroll
        for (int n = 0; n < 2; n++)
#pragma unroll
            for (int j = 0; j < 4; j++) {
                long row = row0 + wr * 64 + m * 16 + g * 4 + j;
                int col = n0 + wc * 32 + n * 16 + c;
                float v = acc[m][n][j] * scale;
                if (BIAS) v += bv[n];
                if (RELU) v = fmaxf(v, 0.f);
                if (OUT_BF16) Cb[row * N + col] = (bf16)v;
                else Cf[row * N + col] = v;
            }
}

// ------------- 128x128 MFMA GEMM (big GEMMs) -------------
template<int OUT_BF16>
__global__ __launch_bounds__(256) void mfma_gemm128(
    const bf16* __restrict__ A, const bf16* __restrict__ Bt,
    void* __restrict__ Cv, int N, int K, float scale,
    long sA, long sB, long sC)
{
    __shared__ bf16 As[128][32];
    __shared__ bf16 Bs[128][32];
    int tid = threadIdx.x;
    int lane = tid & 63, w = tid >> 6;
    int wr = w >> 1, wc = w & 1;
    int g = lane >> 4, c = lane & 15;
    long z = blockIdx.z;
    const bf16* Ab = A + z * sA;
    const bf16* Bb = Bt + z * sB;
    long row0 = (long)blockIdx.y * 128;
    int n0 = blockIdx.x * 128;

    f32x4 acc[4][4];
#pragma unroll
    for (int m = 0; m < 4; m++)
#pragma unroll
        for (int n = 0; n < 4; n++) acc[m][n] = (f32x4){0.f, 0.f, 0.f, 0.f};

    for (int k0 = 0; k0 < K; k0 += 32) {
        __syncthreads();
        const bf16* ga = Ab + (row0 + w * 16 + (lane >> 2)) * K + k0 + (lane & 3) * 8;
        gload16(ga, &As[w * 16][0]);
        gload16(ga + (long)64 * K, &As[w * 16 + 64][0]);
        const bf16* gb = Bb + (long)(n0 + w * 16 + (lane >> 2)) * K + k0 + (lane & 3) * 8;
        gload16(gb, &Bs[w * 16][0]);
        gload16(gb + (long)64 * K, &Bs[w * 16 + 64][0]);
        __syncthreads();
        bf16x8 af[4], bfr[4];
#pragma unroll
        for (int m = 0; m < 4; m++)
            af[m] = *(const bf16x8*)&As[wr * 64 + m * 16 + c][g * 8];
#pragma unroll
        for (int n = 0; n < 4; n++)
            bfr[n] = *(const bf16x8*)&Bs[wc * 64 + n * 16 + c][g * 8];
#pragma unroll
        for (int m = 0; m < 4; m++)
#pragma unroll
            for (int n = 0; n < 4; n++)
                acc[m][n] = mfma16(af[m], bfr[n], acc[m][n]);
    }

    float* Cf = (float*)Cv + z * sC;
    bf16* Cb = (bf16*)Cv + z * sC;
#pragma unroll
    for (int m = 0; m < 4; m++)
#pragma unroll
        for (int n = 0; n < 4; n++)
#pragma unroll
            for (int j = 0; j < 4; j++) {
                long row = row0 + wr * 64 + m * 16 + g * 4 + j;
                int col = n0 + wc * 64 + n * 16 + c;
                float v = acc[m][n][j] * scale;
                if (OUT_BF16) Cb[row * N + col] = (bf16)v;
                else Cf[row * N + col] = v;
            }
}

// ------------- MFMA flash attention (K+V in LDS, XCD-swizzled) -------------
// Flat grid 1024 blocks = (16 qb, 32 bh, 2 sp), XCD k owns bh 4k..4k+3.
// Block = 4 waves x 16 q-rows. K tile and V tile (64x64) staged in LDS,
// double-buffered via global_load_lds with pre-swizzled source columns.
// LDS: 16K (K) + 16K (V) + 8K (P, XOR-swizzled) = 40KB -> 4 blocks/CU.
__global__ __launch_bounds__(256, 4) void attn_mfma(
    const bf16* __restrict__ QP, const bf16* __restrict__ KP,
    const bf16* __restrict__ Vt, const unsigned* __restrict__ bits,
    bf16* __restrict__ Opart, float* __restrict__ Mpart,
    float* __restrict__ Lpart)
{
    __shared__ bf16 Kls[2][4096];      // [buf][64 keys x 64 d], swizzled
    __shared__ bf16 Vls[2][4096];      // [buf][64 d x 64 keys], swizzled
    __shared__ bf16 Pl[4][1024];       // per-wave P [q=c][64 keys], XOR-swizzled

    int tid = threadIdx.x;
    int lane = tid & 63, wv = tid >> 6;
    int g = lane >> 4, c = lane & 15;

    int flat = blockIdx.x;
    int logical = (flat & 7) * 128 + (flat >> 3);   // XCD-chunked
    int bh = logical >> 5;
    int rr = logical & 31;
    int sp = rr >> 4;
    int q0 = (rr & 15) * 64 + wv * 16;
    int b = bh >> 3;

    long qrow0 = (long)bh * 1024 + q0;
    long krow0 = (long)bh * 2048 + (long)sp * 1024;
    const bf16* vtb = Vt + (long)bh * 131072 + (long)sp * 1024;
    const unsigned* bitrow = bits + ((long)b * 1024 + q0 + c) * 64 + sp * 32;

    // staging geometry: lane l covers row (l>>3), 16B chunk (l&7)^(l>>3)
    int lr = lane >> 3, lc = lane & 7;
    int scol = (lc ^ lr) * 8;                       // pre-swizzled src col (elems)
    int cs = c & 7;                                  // read-side XOR key

    bf16x8 qa[2];
#pragma unroll
    for (int hh = 0; hh < 2; hh++)
        qa[hh] = *(const bf16x8*)(QP + (qrow0 + c) * 64 + hh * 32 + g * 8);

    f32x4 o_acc[4];
#pragma unroll
    for (int ot = 0; ot < 4; ot++) o_acc[ot] = (f32x4){0.f, 0.f, 0.f, 0.f};
    float m_r = -1e30f, l_r = 0.f;

    // prologue: stage tile 0 (K and V)
    {
        const bf16* sk = KP + (krow0 + wv * 16 + lr) * 64 + scol;
        gload16(sk, &Kls[0][(wv * 16) * 64]);
        gload16(sk + 8 * 64, &Kls[0][(wv * 16 + 8) * 64]);
        const bf16* sv = vtb + (long)(wv * 16 + lr) * 2048 + scol;
        gload16(sv, &Vls[0][(wv * 16) * 64]);
        gload16(sv + 8 * 2048, &Vls[0][(wv * 16 + 8) * 64]);
    }
    uint2 wp_nxt = *(const uint2*)(bitrow);
    __syncthreads();

    const int NT = LKK / KSPLIT / 64;   // 16
    for (int kt = 0; kt < NT; kt++) {
        int cur = kt & 1;
        // prefetch next K+V tiles into other buffer
        if (kt + 1 < NT) {
            int kn = (kt + 1) * 64;
            const bf16* sk = KP + (krow0 + kn + wv * 16 + lr) * 64 + scol;
            gload16(sk, &Kls[cur ^ 1][(wv * 16) * 64]);
            gload16(sk + 8 * 64, &Kls[cur ^ 1][(wv * 16 + 8) * 64]);
            const bf16* sv = vtb + (long)(wv * 16 + lr) * 2048 + kn + scol;
            gload16(sv, &Vls[cur ^ 1][(wv * 16) * 64]);
            gload16(sv + 8 * 2048, &Vls[cur ^ 1][(wv * 16 + 8) * 64]);
        }
        uint2 wp = wp_nxt;
        if (kt + 1 < NT) wp_nxt = *(const uint2*)(bitrow + (kt + 1) * 2);

        // S^T = K Q^T from LDS (swizzled read)
        const char* kls = (const char*)&Kls[cur][0];
        f32x4 s[4];
#pragma unroll
        for (int mt = 0; mt < 4; mt++) {
            bf16x8 ka0 = *(const bf16x8*)(kls + (mt * 16 + c) * 128 + ((g ^ cs) << 4));
            bf16x8 ka1 = *(const bf16x8*)(kls + (mt * 16 + c) * 128 + (((4 + g) ^ cs) << 4));
            s[mt] = mfma16(ka0, qa[0], (f32x4){0.f, 0.f, 0.f, 0.f});
            s[mt] = mfma16(ka1, qa[1], s[mt]);
        }

        // mask + scale (lane's q = c)
#pragma unroll
        for (int mt = 0; mt < 4; mt++)
#pragma unroll
            for (int j = 0; j < 4; j++) {
                int kl = mt * 16 + 4 * g + j;
                unsigned wsel = (kl < 32) ? wp.x : wp.y;
                s[mt][j] = ((wsel >> (kl & 31)) & 1) ? -1e30f : s[mt][j] * 0.125f;
            }

        // online softmax with defer-max (THR=8)
        float mx = -1e30f;
#pragma unroll
        for (int mt = 0; mt < 4; mt++)
            mx = fmaxf(mx, fmaxf(fmaxf(s[mt][0], s[mt][1]),
                                 fmaxf(s[mt][2], s[mt][3])));
        mx = fmaxf(mx, __shfl_xor(mx, 16, 64));
        mx = fmaxf(mx, __shfl_xor(mx, 32, 64));

        float fct = 1.f;
        if (__any(mx > m_r + 8.f)) {
            float mnew = fmaxf(m_r, mx);
            fct = __expf(m_r - mnew);
            m_r = mnew;
            float fq[4];
#pragma unroll
            for (int j = 0; j < 4; j++)
                fq[j] = __shfl(fct, (lane & 48) | (4 * g + j), 64);
#pragma unroll
            for (int ot = 0; ot < 4; ot++)
#pragma unroll
                for (int j = 0; j < 4; j++) o_acc[ot][j] *= fq[j];
        }

        float sum = 0.f;
#pragma unroll
        for (int mt = 0; mt < 4; mt++)
#pragma unroll
            for (int j = 0; j < 4; j++) {
                float p = __expf(s[mt][j] - m_r);
                s[mt][j] = p;
                sum += p;
            }
        sum += __shfl_xor(sum, 16, 64);
        sum += __shfl_xor(sum, 32, 64);
        l_r = l_r * fct + sum;

        // P -> per-wave LDS, XOR-swizzled [q=c][k]: 8B store per mt
        char* plb = (char*)&Pl[wv][0];
#pragma unroll
        for (int mt = 0; mt < 4; mt++) {
            bf16x4 pk;
#pragma unroll
            for (int j = 0; j < 4; j++) pk[j] = (bf16)s[mt][j];
            int wch = (mt * 2 + (g >> 1)) ^ cs;
            *(bf16x4*)(plb + c * 128 + (wch << 4) + (g & 1) * 8) = pk;
        }

        // PV: O[q][d] += P[q][k] V[d][k], both operands from swizzled LDS
        const char* vls = (const char*)&Vls[cur][0];
#pragma unroll
        for (int kh = 0; kh < 2; kh++) {
            bf16x8 pa = *(const bf16x8*)(plb + c * 128 + ((((kh << 2) + g) ^ cs) << 4));
#pragma unroll
            for (int ot = 0; ot < 4; ot++) {
                bf16x8 vbf = *(const bf16x8*)
                    (vls + (ot * 16 + c) * 128 + ((((kh << 2) + g) ^ cs) << 4));
                o_acc[ot] = mfma16(pa, vbf, o_acc[ot]);
            }
        }
        __syncthreads();   // next-tile staging complete + buffers reusable
    }

    // write raw partials
    long ob = ((long)sp * NROWS + qrow0) * 64;
#pragma unroll
    for (int ot = 0; ot < 4; ot++)
#pragma unroll
        for (int j = 0; j < 4; j++)
            Opart[ob + (long)(4 * g + j) * 64 + ot * 16 + c] = (bf16)o_acc[ot][j];
    if (g == 0) {
        Mpart[(long)sp * NROWS + qrow0 + c] = m_r;
        Lpart[(long)sp * NROWS + qrow0 + c] = l_r;
    }
}

// ------------- combine k-split partials -------------
__global__ __launch_bounds__(256) void attn_combine(
    const bf16* __restrict__ Op, const float* __restrict__ Mp,
    const float* __restrict__ Lp, bf16* __restrict__ O)
{
    long idx = (long)blockIdx.x * 256 + threadIdx.x;
    long row = idx >> 6;
    float m0 = Mp[row], m1 = Mp[NROWS + row];
    float l0 = Lp[row], l1 = Lp[NROWS + row];
    float mm = fmaxf(m0, m1);
    float e0 = __expf(m0 - mm), e1 = __expf(m1 - mm);
    float inv = 1.f / (l0 * e0 + l1 * e1);
    float o = ((float)Op[idx] * e0 + (float)Op[(long)NROWS * 64 + idx] * e1) * inv;
    O[idx] = (bf16)o;
}

// ------------- LN(residual) -------------
__global__ __launch_bounds__(256) void ln_kernel(
    const float* __restrict__ res, const float* __restrict__ y,
    const float* __restrict__ g, const float* __restrict__ bb,
    float* __restrict__ outf, bf16* __restrict__ outb)
{
    int wave = threadIdx.x >> 6, lane = threadIdx.x & 63;
    long row = (long)blockIdx.x * 4 + wave;
    const float* rp = res + row * D_MODEL;
    const float* yp = y + row * D_MODEL;
    float v[8];
    float s = 0.f, sq = 0.f;
#pragma unroll
    for (int j = 0; j < 8; j++) {
        int col = lane + 64 * j;
        v[j] = rp[col] + yp[col];
        s += v[j]; sq += v[j] * v[j];
    }
#pragma unroll
    for (int o = 32; o > 0; o >>= 1) {
        s += __shfl_down(s, o, 64);
        sq += __shfl_down(sq, o, 64);
    }
    s = __shfl(s, 0, 64);
    sq = __shfl(sq, 0, 64);
    float mean = s * (1.f / 512.f);
    float var = sq * (1.f / 512.f) - mean * mean;
    float rstd = rsqrtf(fmaxf(var, 0.f) + 1e-5f);
    float* opf = outf + row * D_MODEL;
    bf16* opb = outb + row * D_MODEL;
#pragma unroll
    for (int j = 0; j < 8; j++) {
        int col = lane + 64 * j;
        float o = (v[j] - mean) * rstd * g[col] + bb[col];
        opf[col] = o;
        opb[col] = (bf16)o;
    }
}

extern "C" void kernel_launch(void* const* d_in, const int* in_sizes, int n_in,
                              void* d_out, int out_size, void* d_ws, size_t ws_size,
                              hipStream_t stream)
{
    const float* x    = (const float*)d_in[0];
    const float* hin  = (const float*)d_in[1];
    const int*   mask = (const int*)d_in[2];
    const float* wq   = (const float*)d_in[3];
    const float* wk   = (const float*)d_in[4];
    const float* wv   = (const float*)d_in[5];
    const float* wo   = (const float*)d_in[6];
    const float* ffw1 = (const float*)d_in[7];
    const float* ffb1 = (const float*)d_in[8];
    const float* ffw2 = (const float*)d_in[9];
    const float* ffb2 = (const float*)d_in[10];
    const float* g1   = (const float*)d_in[11];
    const float* be1  = (const float*)d_in[12];
    const float* g2   = (const float*)d_in[13];
    const float* be2  = (const float*)d_in[14];
    const float* out_wq = (const float*)d_in[15];
    const float* out_wk = (const float*)d_in[16];
    float* out = (float*)d_out;

    const long NQ = (long)BB * LQ;   // 4096
    const long NK = (long)BB * LKK;  // 8192
    const long WSZ = 512L * 512;

    // workspace layout (bytes). SH region time-shares y_f / V-plane / Opart.
    char* W = (char*)d_ws;
    float* h_f  = (float*)(W);                      // 8 MB
    char*  SH   = W + 8388608;                      // 8 MB shared region
    float* y_f  = (float*)SH;
    bf16*  v_pl = (bf16*)SH;
    bf16*  opart= (bf16*)SH;
    bf16*  h_b  = (bf16*)(W + 16777216);            // 4 MB
    bf16*  x_b  = (bf16*)(W + 20971520);            // 8 MB
    bf16*  q_b  = (bf16*)(W + 29360128);            // 4 MB
    bf16*  a_b  = (bf16*)(W + 33554432);            // 4 MB
    bf16*  k_pl = (bf16*)(W + 37748736);            // 8 MB
    bf16*  vt   = (bf16*)(W + 46137344);            // 8 MB
    bf16*  wts  = (bf16*)(W + 54525952);            // 10 MB
    bf16*  wtQ  = wts;
    bf16*  wtO  = wts + 3 * WSZ;
    bf16*  wtF1 = wts + 6 * WSZ;
    bf16*  wtF2 = wts + 9 * WSZ;
    bf16*  wtKV = wts + 12 * WSZ;                   // K0,V0,K1,V1,K2,V2,OutK
    bf16*  wtOQ = wts + 19 * WSZ;
    unsigned* mb = (unsigned*)(W + 65011712);       // 1 MB
    float* Mpart = (float*)(W + 66060288);          // 256 KB
    float* Lpart = (float*)(W + 66322432);          // 256 KB

    const long sKV = ((bf16*)SH) - k_pl;            // element offset K-plane -> V-plane

    dim3 blk(256);

    // preprocessing
    hipMemcpyAsync(h_f, hin, NQ * D_MODEL * sizeof(float),
                   hipMemcpyDeviceToDevice, stream);
    cast_kernel<<<dim3((NK * D_MODEL / 4 + 255) / 256), blk, 0, stream>>>(x, x_b, NK * D_MODEL);
    cast_kernel<<<dim3((NQ * D_MODEL / 4 + 255) / 256), blk, 0, stream>>>(hin, h_b, NQ * D_MODEL);
    dim3 gt(16, 16, 3);
    tcast_kernel<<<gt, blk, 0, stream>>>(wq, wtQ, WSZ);
    tcast_kernel<<<gt, blk, 0, stream>>>(wo, wtO, WSZ);
    tcast_kernel<<<gt, blk, 0, stream>>>(ffw1, wtF1, WSZ);
    tcast_kernel<<<gt, blk, 0, stream>>>(ffw2, wtF2, WSZ);
    tcast_kernel<<<gt, blk, 0, stream>>>(wk, wtKV, 2 * WSZ);
    tcast_kernel<<<gt, blk, 0, stream>>>(wv, wtKV + WSZ, 2 * WSZ);
    dim3 gt1(16, 16, 1);
    tcast_kernel<<<gt1, blk, 0, stream>>>(out_wk, wtKV + 6 * WSZ, 0);
    tcast_kernel<<<gt1, blk, 0, stream>>>(out_wq, wtOQ, 0);
    maskbits_kernel<<<dim3(32768), blk, 0, stream>>>(mask, mb);

    dim3 gq(8, 32, 1);           // 4096 x 512 (128x64)
    dim3 gkv(4, 64, 2);          // 8192 x 512, z = {K,V} (128x128)
    dim3 gvt(32, 32);
    dim3 ga(1024);               // flat, XCD-swizzled inside
    dim3 gc(NROWS * 64 / 256);

    for (int i = 0; i < NL; i++) {
        mfma_gemm<0,0,1><<<gq, blk, 0, stream>>>(h_b, wtQ + i * WSZ, nullptr, q_b,
            512, 512, 1.f, 0, 0, 0);
        mfma_gemm128<1><<<gkv, blk, 0, stream>>>(x_b, wtKV + 2 * i * WSZ, k_pl,
            512, 512, 1.f, 0, WSZ, sKV);
        vtrans_kernel<<<gvt, blk, 0, stream>>>(v_pl, vt);

        attn_mfma<<<ga, blk, 0, stream>>>(q_b, k_pl, vt, mb, opart, Mpart, Lpart);
        attn_combine<<<gc, blk, 0, stream>>>(opart, Mpart, Lpart, a_b);

        mfma_gemm<0,0,0><<<gq, blk, 0, stream>>>(a_b, wtO + i * WSZ, nullptr, y_f,
            512, 512, 1.f, 0, 0, 0);
        ln_kernel<<<dim3(NQ / 4), blk, 0, stream>>>(h_f, y_f,
            g1 + i * D_MODEL, be1 + i * D_MODEL, h_f, h_b);

        mfma_gemm<1,1,1><<<gq, blk, 0, stream>>>(h_b, wtF1 + i * WSZ,
            ffb1 + i * D_MODEL, q_b, 512, 512, 1.f, 0, 0, 0);
        mfma_gemm<1,0,0><<<gq, blk, 0, stream>>>(q_b, wtF2 + i * WSZ,
            ffb2 + i * D_MODEL, y_f, 512, 512, 1.f, 0, 0, 0);
        ln_kernel<<<dim3(NQ / 4), blk, 0, stream>>>(h_f, y_f,
            g2 + i * D_MODEL, be2 + i * D_MODEL, h_f, h_b);
    }

    // final scores
    mfma_gemm<0,0,1><<<gq, blk, 0, stream>>>(h_b, wtOQ, nullptr, q_b,
        512, 512, 1.f, 0, 0, 0);
    dim3 gkf(4, 64, 1);
    mfma_gemm128<1><<<gkf, blk, 0, stream>>>(x_b, wtKV + 6 * WSZ, k_pl,
        512, 512, 1.f, 0, 0, 0);
    dim3 gf(LKK / 128, LQ / 128, BB);
    mfma_gemm128<0><<<gf, blk, 0, stream>>>(q_b, k_pl, out,
        LKK, 512, 0.04419417382415922f,
        (long)LQ * 512, (long)LKK * 512, (long)LQ * LKK);
}

// Round 7
// 430.193 us; speedup vs baseline: 1.6962x; 1.1048x over previous
//
#include <hip/hip_runtime.h>
#include <math.h>

// bf16-MFMA decoder, round 7.
// - ALL GEMMs double-buffered (prefetch-next-then-compute, 1 barrier/K-step).
// - Q/K/V projections batched into one z=3 launch (also used for final qf/kf).
// - 8 weight transpose-casts merged into one z=20 launch.
// - Attention: exp2-domain softmax (scale folds log2e), K+V LDS dbuf,
//   XCD-swizzled grid, defer-max, KSPLIT=2.

#define D_MODEL 512
#define LQ 1024
#define LKK 2048
#define BB 4
#define NL 3
#define KSPLIT 2
#define NROWS 32768   // packed q-rows total = B*8*1024
#define WSZC 262144L  // elems per 512x512 weight matrix

typedef __bf16 bf16;
typedef __bf16 bf16x8 __attribute__((ext_vector_type(8)));
typedef __bf16 bf16x4 __attribute__((ext_vector_type(4)));
typedef float f32x4 __attribute__((ext_vector_type(4)));

__device__ inline f32x4 mfma16(bf16x8 a, bf16x8 b, f32x4 c) {
    return __builtin_amdgcn_mfma_f32_16x16x32_bf16(a, b, c, 0, 0, 0);
}

__device__ inline void gload16(const void* g, void* l) {
    __builtin_amdgcn_global_load_lds(
        (const __attribute__((address_space(1))) void*)g,
        (__attribute__((address_space(3))) void*)l, 16, 0, 0);
}

// ---------------- cast fp32 -> bf16 ----------------
__global__ __launch_bounds__(256) void cast_kernel(
    const float* __restrict__ in, bf16* __restrict__ out, long n)
{
    long i4 = ((long)blockIdx.x * 256 + threadIdx.x) * 4;
    if (i4 >= n) return;
    float4 v = *(const float4*)(in + i4);
    bf16x4 o;
    o[0] = (bf16)v.x; o[1] = (bf16)v.y; o[2] = (bf16)v.z; o[3] = (bf16)v.w;
    *(bf16x4*)(out + i4) = o;
}

// ------- ALL weight transpose-casts in one launch: z selects matrix -------
// z 0..2 wq, 3..5 wo, 6..8 ffw1, 9..11 ffw2, 12..14 wk, 15..17 wv,
// 18 out_wq, 19 out_wk. Dst layout matches round-6 workspace map.
__global__ __launch_bounds__(256) void tcast_all(
    const float* __restrict__ wq, const float* __restrict__ wo,
    const float* __restrict__ f1, const float* __restrict__ f2,
    const float* __restrict__ wk, const float* __restrict__ wv,
    const float* __restrict__ owq, const float* __restrict__ owk,
    bf16* __restrict__ wts, bf16* __restrict__ wtOQ)
{
    __shared__ float t[32][33];
    int z = blockIdx.z;
    const float* src; bf16* dst;
    if (z < 3)       { src = wq  + z * WSZC;        dst = wts + (long)z * WSZC; }
    else if (z < 6)  { src = wo  + (z - 3) * WSZC;  dst = wts + (long)z * WSZC; }
    else if (z < 9)  { src = f1  + (z - 6) * WSZC;  dst = wts + (long)z * WSZC; }
    else if (z < 12) { src = f2  + (z - 9) * WSZC;  dst = wts + (long)z * WSZC; }
    else if (z < 15) { src = wk  + (z - 12) * WSZC; dst = wts + (12 + 2 * (z - 12)) * WSZC; }
    else if (z < 18) { src = wv  + (z - 15) * WSZC; dst = wts + (13 + 2 * (z - 15)) * WSZC; }
    else if (z == 18){ src = owq;                   dst = wtOQ; }
    else             { src = owk;                   dst = wts + 18 * WSZC; }

    int tx = threadIdx.x & 31, ty = threadIdx.x >> 5;
    int x0 = blockIdx.x * 32, y0 = blockIdx.y * 32;
#pragma unroll
    for (int i = 0; i < 4; i++)
        t[ty + 8 * i][tx] = src[(long)(y0 + ty + 8 * i) * 512 + x0 + tx];
    __syncthreads();
#pragma unroll
    for (int i = 0; i < 4; i++)
        dst[(long)(x0 + ty + 8 * i) * 512 + y0 + tx] = (bf16)t[tx][ty + 8 * i];
}

// ------------- mask (int32) -> packed bits -------------
__global__ __launch_bounds__(256) void maskbits_kernel(
    const int* __restrict__ m, unsigned* __restrict__ bits)
{
    long i = (long)blockIdx.x * 256 + threadIdx.x;
    int v = m[i] != 0;
    unsigned long long bal = __ballot(v);
    int lane = threadIdx.x & 63;
    if (lane == 0) bits[i >> 5] = (unsigned)bal;
    else if (lane == 32) bits[i >> 5] = (unsigned)(bal >> 32);
}

// ------------- V transpose: v[(bh)*2048+p][64] -> vt[(bh)*64+d][2048] -------------
__global__ __launch_bounds__(256) void vtrans_kernel(
    const bf16* __restrict__ v, bf16* __restrict__ vt)
{
    __shared__ bf16 t[64][72];
    int bh = blockIdx.y;
    int p0 = blockIdx.x * 64;
    const bf16* vb = v + ((long)bh * 2048 + p0) * 64;
    bf16* vtb = vt + (long)bh * 64 * 2048;
    int tid = threadIdx.x;
#pragma unroll
    for (int it = 0; it < 2; it++) {
        int r = it * 32 + (tid >> 3);
        int c8 = (tid & 7) * 8;
        bf16x8 vv = *(const bf16x8*)(vb + (long)r * 64 + c8);
        *(bf16x8*)&t[r][c8] = vv;
    }
    __syncthreads();
#pragma unroll
    for (int it = 0; it < 2; it++) {
        int d = it * 32 + (tid >> 3);
        int p8 = (tid & 7) * 8;
        bf16x8 ov;
#pragma unroll
        for (int j = 0; j < 8; j++) ov[j] = t[p8 + j][d];
        *(bf16x8*)(vtb + (long)d * 2048 + p0 + p8) = ov;
    }
}

// ------------- 128x64 MFMA GEMM, double-buffered (wo/ff1/ff2) -------------
template<int BIAS, int RELU, int OUT_BF16>
__global__ __launch_bounds__(256) void mfma_gemm(
    const bf16* __restrict__ A, const bf16* __restrict__ Bt,
    const float* __restrict__ bias, void* __restrict__ Cv,
    int N, int K)
{
    __shared__ bf16 As[2][4096];   // 128 x 32
    __shared__ bf16 Bs[2][2048];   // 64 x 32
    int tid = threadIdx.x;
    int lane = tid & 63, w = tid >> 6;
    int wr = w >> 1, wc = w & 1;
    int g = lane >> 4, c = lane & 15;
    long row0 = (long)blockIdx.y * 128;
    int n0 = blockIdx.x * 64;

    f32x4 acc[4][2];
#pragma unroll
    for (int m = 0; m < 4; m++)
#pragma unroll
        for (int n = 0; n < 2; n++) acc[m][n] = (f32x4){0.f, 0.f, 0.f, 0.f};

    int lr4 = lane >> 2, lc8 = (lane & 3) * 8;
    auto STAGE = [&](int buf, int k0) {
        const bf16* ga = A + (row0 + w * 32 + lr4) * (long)K + k0 + lc8;
        gload16(ga, &As[buf][(w * 32) * 32]);
        gload16(ga + (long)16 * K, &As[buf][(w * 32 + 16) * 32]);
        const bf16* gb = Bt + (long)(n0 + w * 16 + lr4) * K + k0 + lc8;
        gload16(gb, &Bs[buf][(w * 16) * 32]);
    };

    STAGE(0, 0);
    __syncthreads();
    int nk = K >> 5;
    for (int it = 0; it < nk; ++it) {
        int cur = it & 1;
        if (it + 1 < nk) STAGE(cur ^ 1, (it + 1) << 5);
        bf16x8 af[4], bfr[2];
#pragma unroll
        for (int m = 0; m < 4; m++)
            af[m] = *(const bf16x8*)&As[cur][(wr * 64 + m * 16 + c) * 32 + g * 8];
#pragma unroll
        for (int n = 0; n < 2; n++)
            bfr[n] = *(const bf16x8*)&Bs[cur][(wc * 32 + n * 16 + c) * 32 + g * 8];
#pragma unroll
        for (int m = 0; m < 4; m++)
#pragma unroll
            for (int n = 0; n < 2; n++)
                acc[m][n] = mfma16(af[m], bfr[n], acc[m][n]);
        __syncthreads();
    }

    float bv[2] = {0.f, 0.f};
    if (BIAS) {
#pragma unroll
        for (int n = 0; n < 2; n++) bv[n] = bias[n0 + wc * 32 + n * 16 + c];
    }
    float* Cf = (float*)Cv;
    bf16* Cb = (bf16*)Cv;
#pragma unroll
    for (int m = 0; m < 4; m++)
#pragma unroll
        for (int n = 0; n < 2; n++)
#pragma unroll
            for (int j = 0; j < 4; j++) {
                long row = row0 + wr * 64 + m * 16 + g * 4 + j;
                int col = n0 + wc * 32 + n * 16 + c;
                float v = acc[m][n][j];
                if (BIAS) v += bv[n];
                if (RELU) v = fmaxf(v, 0.f);
                if (OUT_BF16) Cb[row * N + col] = (bf16)v;
                else Cf[row * N + col] = v;
            }
}

// ------------- 128x128 MFMA GEMM core (double-buffered) -------------
template<int OUT_BF16>
__device__ inline void gemm128_body(
    const bf16* __restrict__ Ab, const bf16* __restrict__ Bb,
    void* __restrict__ Cv, int N, int K, float scale,
    long row0, int n0)
{
    __shared__ bf16 As[2][4096];
    __shared__ bf16 Bs[2][4096];
    int tid = threadIdx.x;
    int lane = tid & 63, w = tid >> 6;
    int wr = w >> 1, wc = w & 1;
    int g = lane >> 4, c = lane & 15;

    f32x4 acc[4][4];
#pragma unroll
    for (int m = 0; m < 4; m++)
#pragma unroll
        for (int n = 0; n < 4; n++) acc[m][n] = (f32x4){0.f, 0.f, 0.f, 0.f};

    int lr4 = lane >> 2, lc8 = (lane & 3) * 8;
    auto STAGE = [&](int buf, int k0) {
        const bf16* ga = Ab + (row0 + w * 16 + lr4) * (long)K + k0 + lc8;
        gload16(ga, &As[buf][(w * 16) * 32]);
        gload16(ga + (long)64 * K, &As[buf][(w * 16 + 64) * 32]);
        const bf16* gb = Bb + (long)(n0 + w * 16 + lr4) * K + k0 + lc8;
        gload16(gb, &Bs[buf][(w * 16) * 32]);
        gload16(gb + (long)64 * K, &Bs[buf][(w * 16 + 64) * 32]);
    };

    STAGE(0, 0);
    __syncthreads();
    int nk = K >> 5;
    for (int it = 0; it < nk; ++it) {
        int cur = it & 1;
        if (it + 1 < nk) STAGE(cur ^ 1, (it + 1) << 5);
        bf16x8 af[4], bfr[4];
#pragma unroll
        for (int m = 0; m < 4; m++)
            af[m] = *(const bf16x8*)&As[cur][(wr * 64 + m * 16 + c) * 32 + g * 8];
#pragma unroll
        for (int n = 0; n < 4; n++)
            bfr[n] = *(const bf16x8*)&Bs[cur][(wc * 64 + n * 16 + c) * 32 + g * 8];
#pragma unroll
        for (int m = 0; m < 4; m++)
#pragma unroll
            for (int n = 0; n < 4; n++)
                acc[m][n] = mfma16(af[m], bfr[n], acc[m][n]);
        __syncthreads();
    }

    float* Cf = (float*)Cv;
    bf16* Cb = (bf16*)Cv;
#pragma unroll
    for (int m = 0; m < 4; m++)
#pragma unroll
        for (int n = 0; n < 4; n++)
#pragma unroll
            for (int j = 0; j < 4; j++) {
                long row = row0 + wr * 64 + m * 16 + g * 4 + j;
                int col = n0 + wc * 64 + n * 16 + c;
                float v = acc[m][n][j] * scale;
                if (OUT_BF16) Cb[row * N + col] = (bf16)v;
                else Cf[row * N + col] = v;
            }
}

// batched final-scores GEMM (fp32 out, scaled)
__global__ __launch_bounds__(256) void mfma_gemm128(
    const bf16* __restrict__ A, const bf16* __restrict__ Bt,
    float* __restrict__ Cv, int N, int K, float scale,
    long sA, long sB, long sC)
{
    long z = blockIdx.z;
    gemm128_body<0>(A + z * sA, Bt + z * sB, Cv + z * sC, N, K, scale,
                    (long)blockIdx.y * 128, blockIdx.x * 128);
}

// Q/K/V (z=3) or qf/kf (z=2) batched projections, 128x128 tiles.
// z==0: A=Ah (M=4096, y<32 only), else A=Ax (M=8192).
__global__ __launch_bounds__(256) void qkv_gemm(
    const bf16* __restrict__ Ah, const bf16* __restrict__ Ax,
    const bf16* __restrict__ B0, const bf16* __restrict__ B1,
    const bf16* __restrict__ B2,
    bf16* __restrict__ C0, bf16* __restrict__ C1, bf16* __restrict__ C2)
{
    int z = blockIdx.z;
    if (z == 0 && blockIdx.y >= 32) return;
    const bf16* A = z ? Ax : Ah;
    const bf16* Bt = (z == 0) ? B0 : (z == 1 ? B1 : B2);
    bf16* C = (z == 0) ? C0 : (z == 1 ? C1 : C2);
    gemm128_body<1>(A, Bt, C, 512, 512, 1.f,
                    (long)blockIdx.y * 128, blockIdx.x * 128);
}

// ------------- MFMA flash attention (K+V in LDS, XCD-swizzled, exp2) -------------
__global__ __launch_bounds__(256, 4) void attn_mfma(
    const bf16* __restrict__ QP, const bf16* __restrict__ KP,
    const bf16* __restrict__ Vt, const unsigned* __restrict__ bits,
    bf16* __restrict__ Opart, float* __restrict__ Mpart,
    float* __restrict__ Lpart)
{
    __shared__ bf16 Kls[2][4096];      // [buf][64 keys x 64 d], swizzled
    __shared__ bf16 Vls[2][4096];      // [buf][64 d x 64 keys], swizzled
    __shared__ bf16 Pl[4][1024];       // per-wave P [q=c][64 keys], XOR-swizzled

    const float C2 = 0.1803368801111243f;   // 0.125 * log2(e)

    int tid = threadIdx.x;
    int lane = tid & 63, wv = tid >> 6;
    int g = lane >> 4, c = lane & 15;

    int flat = blockIdx.x;
    int logical = (flat & 7) * 128 + (flat >> 3);   // XCD-chunked
    int bh = logical >> 5;
    int rr = logical & 31;
    int sp = rr >> 4;
    int q0 = (rr & 15) * 64 + wv * 16;
    int b = bh >> 3;

    long qrow0 = (long)bh * 1024 + q0;
    long krow0 = (long)bh * 2048 + (long)sp * 1024;
    const bf16* vtb = Vt + (long)bh * 131072 + (long)sp * 1024;
    const unsigned* bitrow = bits + ((long)b * 1024 + q0 + c) * 64 + sp * 32;

    int lr = lane >> 3, lc = lane & 7;
    int scol = (lc ^ lr) * 8;                       // pre-swizzled src col
    int cs = c & 7;

    bf16x8 qa[2];
#pragma unroll
    for (int hh = 0; hh < 2; hh++)
        qa[hh] = *(const bf16x8*)(QP + (qrow0 + c) * 64 + hh * 32 + g * 8);

    f32x4 o_acc[4];
#pragma unroll
    for (int ot = 0; ot < 4; ot++) o_acc[ot] = (f32x4){0.f, 0.f, 0.f, 0.f};
    float m_r = -1e30f, l_r = 0.f;

    {
        const bf16* sk = KP + (krow0 + wv * 16 + lr) * 64 + scol;
        gload16(sk, &Kls[0][(wv * 16) * 64]);
        gload16(sk + 8 * 64, &Kls[0][(wv * 16 + 8) * 64]);
        const bf16* sv = vtb + (long)(wv * 16 + lr) * 2048 + scol;
        gload16(sv, &Vls[0][(wv * 16) * 64]);
        gload16(sv + 8 * 2048, &Vls[0][(wv * 16 + 8) * 64]);
    }
    uint2 wp_nxt = *(const uint2*)(bitrow);
    __syncthreads();

    const int NT = LKK / KSPLIT / 64;   // 16
    for (int kt = 0; kt < NT; kt++) {
        int cur = kt & 1;
        if (kt + 1 < NT) {
            int kn = (kt + 1) * 64;
            const bf16* sk = KP + (krow0 + kn + wv * 16 + lr) * 64 + scol;
            gload16(sk, &Kls[cur ^ 1][(wv * 16) * 64]);
            gload16(sk + 8 * 64, &Kls[cur ^ 1][(wv * 16 + 8) * 64]);
            const bf16* sv = vtb + (long)(wv * 16 + lr) * 2048 + kn + scol;
            gload16(sv, &Vls[cur ^ 1][(wv * 16) * 64]);
            gload16(sv + 8 * 2048, &Vls[cur ^ 1][(wv * 16 + 8) * 64]);
        }
        uint2 wp = wp_nxt;
        if (kt + 1 < NT) wp_nxt = *(const uint2*)(bitrow + (kt + 1) * 2);

        // S^T = K Q^T from LDS (swizzled read); scores scaled to log2-domain
        const char* kls = (const char*)&Kls[cur][0];
        f32x4 s[4];
#pragma unroll
        for (int mt = 0; mt < 4; mt++) {
            bf16x8 ka0 = *(const bf16x8*)(kls + (mt * 16 + c) * 128 + ((g ^ cs) << 4));
            bf16x8 ka1 = *(const bf16x8*)(kls + (mt * 16 + c) * 128 + (((4 + g) ^ cs) << 4));
            s[mt] = mfma16(ka0, qa[0], (f32x4){0.f, 0.f, 0.f, 0.f});
            s[mt] = mfma16(ka1, qa[1], s[mt]);
        }

#pragma unroll
        for (int mt = 0; mt < 4; mt++)
#pragma unroll
            for (int j = 0; j < 4; j++) {
                int kl = mt * 16 + 4 * g + j;
                unsigned wsel = (kl < 32) ? wp.x : wp.y;
                s[mt][j] = ((wsel >> (kl & 31)) & 1) ? -1e30f : s[mt][j] * C2;
            }

        // online softmax (log2 domain) with defer-max (THR = 8*log2e)
        float mx = -1e30f;
#pragma unroll
        for (int mt = 0; mt < 4; mt++)
            mx = fmaxf(mx, fmaxf(fmaxf(s[mt][0], s[mt][1]),
                                 fmaxf(s[mt][2], s[mt][3])));
        mx = fmaxf(mx, __shfl_xor(mx, 16, 64));
        mx = fmaxf(mx, __shfl_xor(mx, 32, 64));

        float fct = 1.f;
        if (__any(mx > m_r + 11.5415f)) {
            float mnew = fmaxf(m_r, mx);
            fct = exp2f(m_r - mnew);
            m_r = mnew;
            float fq[4];
#pragma unroll
            for (int j = 0; j < 4; j++)
                fq[j] = __shfl(fct, (lane & 48) | (4 * g + j), 64);
#pragma unroll
            for (int ot = 0; ot < 4; ot++)
#pragma unroll
                for (int j = 0; j < 4; j++) o_acc[ot][j] *= fq[j];
        }

        float sum = 0.f;
#pragma unroll
        for (int mt = 0; mt < 4; mt++)
#pragma unroll
            for (int j = 0; j < 4; j++) {
                float p = exp2f(s[mt][j] - m_r);
                s[mt][j] = p;
                sum += p;
            }
        sum += __shfl_xor(sum, 16, 64);
        sum += __shfl_xor(sum, 32, 64);
        l_r = l_r * fct + sum;

        // P -> per-wave LDS, XOR-swizzled
        char* plb = (char*)&Pl[wv][0];
#pragma unroll
        for (int mt = 0; mt < 4; mt++) {
            bf16x4 pk;
#pragma unroll
            for (int j = 0; j < 4; j++) pk[j] = (bf16)s[mt][j];
            int wch = (mt * 2 + (g >> 1)) ^ cs;
            *(bf16x4*)(plb + c * 128 + (wch << 4) + (g & 1) * 8) = pk;
        }

        // PV
        const char* vls = (const char*)&Vls[cur][0];
#pragma unroll
        for (int kh = 0; kh < 2; kh++) {
            bf16x8 pa = *(const bf16x8*)(plb + c * 128 + ((((kh << 2) + g) ^ cs) << 4));
#pragma unroll
            for (int ot = 0; ot < 4; ot++) {
                bf16x8 vbf = *(const bf16x8*)
                    (vls + (ot * 16 + c) * 128 + ((((kh << 2) + g) ^ cs) << 4));
                o_acc[ot] = mfma16(pa, vbf, o_acc[ot]);
            }
        }
        __syncthreads();
    }

    long ob = ((long)sp * NROWS + qrow0) * 64;
#pragma unroll
    for (int ot = 0; ot < 4; ot++)
#pragma unroll
        for (int j = 0; j < 4; j++)
            Opart[ob + (long)(4 * g + j) * 64 + ot * 16 + c] = (bf16)o_acc[ot][j];
    if (g == 0) {
        Mpart[(long)sp * NROWS + qrow0 + c] = m_r;
        Lpart[(long)sp * NROWS + qrow0 + c] = l_r;
    }
}

// ------------- combine k-split partials (log2-domain stats) -------------
__global__ __launch_bounds__(256) void attn_combine(
    const bf16* __restrict__ Op, const float* __restrict__ Mp,
    const float* __restrict__ Lp, bf16* __restrict__ O)
{
    long idx = (long)blockIdx.x * 256 + threadIdx.x;
    long row = idx >> 6;
    float m0 = Mp[row], m1 = Mp[NROWS + row];
    float l0 = Lp[row], l1 = Lp[NROWS + row];
    float mm = fmaxf(m0, m1);
    float e0 = exp2f(m0 - mm), e1 = exp2f(m1 - mm);
    float inv = 1.f / (l0 * e0 + l1 * e1);
    float o = ((float)Op[idx] * e0 + (float)Op[(long)NROWS * 64 + idx] * e1) * inv;
    O[idx] = (bf16)o;
}

// ------------- LN(residual) -------------
__global__ __launch_bounds__(256) void ln_kernel(
    const float* __restrict__ res, const float* __restrict__ y,
    const float* __restrict__ g, const float* __restrict__ bb,
    float* __restrict__ outf, bf16* __restrict__ outb)
{
    int wave = threadIdx.x >> 6, lane = threadIdx.x & 63;
    long row = (long)blockIdx.x * 4 + wave;
    const float* rp = res + row * D_MODEL;
    const float* yp = y + row * D_MODEL;
    float v[8];
    float s = 0.f, sq = 0.f;
#pragma unroll
    for (int j = 0; j < 8; j++) {
        int col = lane + 64 * j;
        v[j] = rp[col] + yp[col];
        s += v[j]; sq += v[j] * v[j];
    }
#pragma unroll
    for (int o = 32; o > 0; o >>= 1) {
        s += __shfl_down(s, o, 64);
        sq += __shfl_down(sq, o, 64);
    }
    s = __shfl(s, 0, 64);
    sq = __shfl(sq, 0, 64);
    float mean = s * (1.f / 512.f);
    float var = sq * (1.f / 512.f) - mean * mean;
    float rstd = rsqrtf(fmaxf(var, 0.f) + 1e-5f);
    float* opf = outf + row * D_MODEL;
    bf16* opb = outb + row * D_MODEL;
#pragma unroll
    for (int j = 0; j < 8; j++) {
        int col = lane + 64 * j;
        float o = (v[j] - mean) * rstd * g[col] + bb[col];
        opf[col] = o;
        opb[col] = (bf16)o;
    }
}

extern "C" void kernel_launch(void* const* d_in, const int* in_sizes, int n_in,
                              void* d_out, int out_size, void* d_ws, size_t ws_size,
                              hipStream_t stream)
{
    const float* x    = (const float*)d_in[0];
    const float* hin  = (const float*)d_in[1];
    const int*   mask = (const int*)d_in[2];
    const float* wq   = (const float*)d_in[3];
    const float* wk   = (const float*)d_in[4];
    const float* wv   = (const float*)d_in[5];
    const float* wo   = (const float*)d_in[6];
    const float* ffw1 = (const float*)d_in[7];
    const float* ffb1 = (const float*)d_in[8];
    const float* ffw2 = (const float*)d_in[9];
    const float* ffb2 = (const float*)d_in[10];
    const float* g1   = (const float*)d_in[11];
    const float* be1  = (const float*)d_in[12];
    const float* g2   = (const float*)d_in[13];
    const float* be2  = (const float*)d_in[14];
    const float* out_wq = (const float*)d_in[15];
    const float* out_wk = (const float*)d_in[16];
    float* out = (float*)d_out;

    const long NQ = (long)BB * LQ;   // 4096
    const long NK = (long)BB * LKK;  // 8192

    // workspace layout (bytes). SH region time-shares y_f / V-plane / Opart.
    char* W = (char*)d_ws;
    float* h_f  = (float*)(W);                      // 8 MB
    char*  SH   = W + 8388608;                      // 8 MB shared region
    float* y_f  = (float*)SH;
    bf16*  v_pl = (bf16*)SH;
    bf16*  opart= (bf16*)SH;
    bf16*  h_b  = (bf16*)(W + 16777216);            // 4 MB
    bf16*  x_b  = (bf16*)(W + 20971520);            // 8 MB
    bf16*  q_b  = (bf16*)(W + 29360128);            // 4 MB
    bf16*  a_b  = (bf16*)(W + 33554432);            // 4 MB
    bf16*  k_pl = (bf16*)(W + 37748736);            // 8 MB
    bf16*  vt   = (bf16*)(W + 46137344);            // 8 MB
    bf16*  wts  = (bf16*)(W + 54525952);            // wts: 19 matrices (9.5 MB)
    // wts map: 0..2 wtQ, 3..5 wtO, 6..8 wtF1, 9..11 wtF2,
    //          12..17 interleaved K0,V0,K1,V1,K2,V2, 18 out_wk
    bf16*  wtOQ = wts + 19 * WSZC;                  // +0.5 MB (total 10 MB)
    unsigned* mb = (unsigned*)(W + 65011712);       // 1 MB
    float* Mpart = (float*)(W + 66060288);          // 256 KB
    float* Lpart = (float*)(W + 66322432);          // 256 KB

    dim3 blk(256);

    // preprocessing
    hipMemcpyAsync(h_f, hin, NQ * D_MODEL * sizeof(float),
                   hipMemcpyDeviceToDevice, stream);
    cast_kernel<<<dim3((NK * D_MODEL / 4 + 255) / 256), blk, 0, stream>>>(x, x_b, NK * D_MODEL);
    cast_kernel<<<dim3((NQ * D_MODEL / 4 + 255) / 256), blk, 0, stream>>>(hin, h_b, NQ * D_MODEL);
    tcast_all<<<dim3(16, 16, 20), blk, 0, stream>>>(
        wq, wo, ffw1, ffw2, wk, wv, out_wq, out_wk, wts, wtOQ);
    maskbits_kernel<<<dim3(32768), blk, 0, stream>>>(mask, mb);

    dim3 gq(8, 32, 1);           // 4096 x 512 (128x64)
    dim3 gqkv(4, 64, 3);         // z: Q(4096) / K(8192) / V(8192), 128x128
    dim3 gvt(32, 32);
    dim3 ga(1024);               // flat, XCD-swizzled inside
    dim3 gc(NROWS * 64 / 256);

    for (int i = 0; i < NL; i++) {
        qkv_gemm<<<gqkv, blk, 0, stream>>>(h_b, x_b,
            wts + i * WSZC, wts + (12 + 2 * i) * WSZC, wts + (13 + 2 * i) * WSZC,
            q_b, k_pl, v_pl);
        vtrans_kernel<<<gvt, blk, 0, stream>>>(v_pl, vt);

        attn_mfma<<<ga, blk, 0, stream>>>(q_b, k_pl, vt, mb, opart, Mpart, Lpart);
        attn_combine<<<gc, blk, 0, stream>>>(opart, Mpart, Lpart, a_b);

        mfma_gemm<0,0,0><<<gq, blk, 0, stream>>>(a_b, wts + (3 + i) * WSZC,
            nullptr, y_f, 512, 512);
        ln_kernel<<<dim3(NQ / 4), blk, 0, stream>>>(h_f, y_f,
            g1 + i * D_MODEL, be1 + i * D_MODEL, h_f, h_b);

        mfma_gemm<1,1,1><<<gq, blk, 0, stream>>>(h_b, wts + (6 + i) * WSZC,
            ffb1 + i * D_MODEL, q_b, 512, 512);
        mfma_gemm<1,0,0><<<gq, blk, 0, stream>>>(q_b, wts + (9 + i) * WSZC,
            ffb2 + i * D_MODEL, y_f, 512, 512);
        ln_kernel<<<dim3(NQ / 4), blk, 0, stream>>>(h_f, y_f,
            g2 + i * D_MODEL, be2 + i * D_MODEL, h_f, h_b);
    }

    // final: qf = h@out_wq (z=0), kf = x@out_wk (z=1) in one batched launch
    dim3 gqk(4, 64, 2);
    qkv_gemm<<<gqk, blk, 0, stream>>>(h_b, x_b,
        wtOQ, wts + 18 * WSZC, wts + 18 * WSZC, q_b, k_pl, k_pl);

    dim3 gf(LKK / 128, LQ / 128, BB);
    mfma_gemm128<<<gf, blk, 0, stream>>>(q_b, k_pl, out,
        LKK, 512, 0.04419417382415922f,
        (long)LQ * 512, (long)LKK * 512, (long)LQ * LKK);
}

// Round 8
// 410.705 us; speedup vs baseline: 1.7767x; 1.0474x over previous
//
#include <hip/hip_runtime.h>
#include <math.h>

// bf16-MFMA decoder, round 8.
// vs r7: attn softmax uses __builtin_amdgcn_exp2f (single v_exp_f32; the r7
// exp2f libcall was a ~15-inst precise path = the regression), and the
// 0.125*log2e score scale is folded into the Q-projection epilogue.

#define D_MODEL 512
#define LQ 1024
#define LKK 2048
#define BB 4
#define NL 3
#define KSPLIT 2
#define NROWS 32768   // packed q-rows total = B*8*1024
#define WSZC 262144L  // elems per 512x512 weight matrix

typedef __bf16 bf16;
typedef __bf16 bf16x8 __attribute__((ext_vector_type(8)));
typedef __bf16 bf16x4 __attribute__((ext_vector_type(4)));
typedef float f32x4 __attribute__((ext_vector_type(4)));

__device__ inline f32x4 mfma16(bf16x8 a, bf16x8 b, f32x4 c) {
    return __builtin_amdgcn_mfma_f32_16x16x32_bf16(a, b, c, 0, 0, 0);
}

__device__ inline void gload16(const void* g, void* l) {
    __builtin_amdgcn_global_load_lds(
        (const __attribute__((address_space(1))) void*)g,
        (__attribute__((address_space(3))) void*)l, 16, 0, 0);
}

__device__ inline float fexp2(float x) { return __builtin_amdgcn_exp2f(x); }

// ---------------- cast fp32 -> bf16 ----------------
__global__ __launch_bounds__(256) void cast_kernel(
    const float* __restrict__ in, bf16* __restrict__ out, long n)
{
    long i4 = ((long)blockIdx.x * 256 + threadIdx.x) * 4;
    if (i4 >= n) return;
    float4 v = *(const float4*)(in + i4);
    bf16x4 o;
    o[0] = (bf16)v.x; o[1] = (bf16)v.y; o[2] = (bf16)v.z; o[3] = (bf16)v.w;
    *(bf16x4*)(out + i4) = o;
}

// ------- ALL weight transpose-casts in one launch: z selects matrix -------
__global__ __launch_bounds__(256) void tcast_all(
    const float* __restrict__ wq, const float* __restrict__ wo,
    const float* __restrict__ f1, const float* __restrict__ f2,
    const float* __restrict__ wk, const float* __restrict__ wv,
    const float* __restrict__ owq, const float* __restrict__ owk,
    bf16* __restrict__ wts, bf16* __restrict__ wtOQ)
{
    __shared__ float t[32][33];
    int z = blockIdx.z;
    const float* src; bf16* dst;
    if (z < 3)       { src = wq  + z * WSZC;        dst = wts + (long)z * WSZC; }
    else if (z < 6)  { src = wo  + (z - 3) * WSZC;  dst = wts + (long)z * WSZC; }
    else if (z < 9)  { src = f1  + (z - 6) * WSZC;  dst = wts + (long)z * WSZC; }
    else if (z < 12) { src = f2  + (z - 9) * WSZC;  dst = wts + (long)z * WSZC; }
    else if (z < 15) { src = wk  + (z - 12) * WSZC; dst = wts + (12 + 2 * (z - 12)) * WSZC; }
    else if (z < 18) { src = wv  + (z - 15) * WSZC; dst = wts + (13 + 2 * (z - 15)) * WSZC; }
    else if (z == 18){ src = owq;                   dst = wtOQ; }
    else             { src = owk;                   dst = wts + 18 * WSZC; }

    int tx = threadIdx.x & 31, ty = threadIdx.x >> 5;
    int x0 = blockIdx.x * 32, y0 = blockIdx.y * 32;
#pragma unroll
    for (int i = 0; i < 4; i++)
        t[ty + 8 * i][tx] = src[(long)(y0 + ty + 8 * i) * 512 + x0 + tx];
    __syncthreads();
#pragma unroll
    for (int i = 0; i < 4; i++)
        dst[(long)(x0 + ty + 8 * i) * 512 + y0 + tx] = (bf16)t[tx][ty + 8 * i];
}

// ------------- mask (int32) -> packed bits -------------
__global__ __launch_bounds__(256) void maskbits_kernel(
    const int* __restrict__ m, unsigned* __restrict__ bits)
{
    long i = (long)blockIdx.x * 256 + threadIdx.x;
    int v = m[i] != 0;
    unsigned long long bal = __ballot(v);
    int lane = threadIdx.x & 63;
    if (lane == 0) bits[i >> 5] = (unsigned)bal;
    else if (lane == 32) bits[i >> 5] = (unsigned)(bal >> 32);
}

// ------------- V transpose: v[(bh)*2048+p][64] -> vt[(bh)*64+d][2048] -------------
__global__ __launch_bounds__(256) void vtrans_kernel(
    const bf16* __restrict__ v, bf16* __restrict__ vt)
{
    __shared__ bf16 t[64][72];
    int bh = blockIdx.y;
    int p0 = blockIdx.x * 64;
    const bf16* vb = v + ((long)bh * 2048 + p0) * 64;
    bf16* vtb = vt + (long)bh * 64 * 2048;
    int tid = threadIdx.x;
#pragma unroll
    for (int it = 0; it < 2; it++) {
        int r = it * 32 + (tid >> 3);
        int c8 = (tid & 7) * 8;
        bf16x8 vv = *(const bf16x8*)(vb + (long)r * 64 + c8);
        *(bf16x8*)&t[r][c8] = vv;
    }
    __syncthreads();
#pragma unroll
    for (int it = 0; it < 2; it++) {
        int d = it * 32 + (tid >> 3);
        int p8 = (tid & 7) * 8;
        bf16x8 ov;
#pragma unroll
        for (int j = 0; j < 8; j++) ov[j] = t[p8 + j][d];
        *(bf16x8*)(vtb + (long)d * 2048 + p0 + p8) = ov;
    }
}

// ------------- 128x64 MFMA GEMM, double-buffered (wo/ff1/ff2) -------------
template<int BIAS, int RELU, int OUT_BF16>
__global__ __launch_bounds__(256) void mfma_gemm(
    const bf16* __restrict__ A, const bf16* __restrict__ Bt,
    const float* __restrict__ bias, void* __restrict__ Cv,
    int N, int K)
{
    __shared__ bf16 As[2][4096];   // 128 x 32
    __shared__ bf16 Bs[2][2048];   // 64 x 32
    int tid = threadIdx.x;
    int lane = tid & 63, w = tid >> 6;
    int wr = w >> 1, wc = w & 1;
    int g = lane >> 4, c = lane & 15;
    long row0 = (long)blockIdx.y * 128;
    int n0 = blockIdx.x * 64;

    f32x4 acc[4][2];
#pragma unroll
    for (int m = 0; m < 4; m++)
#pragma unroll
        for (int n = 0; n < 2; n++) acc[m][n] = (f32x4){0.f, 0.f, 0.f, 0.f};

    int lr4 = lane >> 2, lc8 = (lane & 3) * 8;
    auto STAGE = [&](int buf, int k0) {
        const bf16* ga = A + (row0 + w * 32 + lr4) * (long)K + k0 + lc8;
        gload16(ga, &As[buf][(w * 32) * 32]);
        gload16(ga + (long)16 * K, &As[buf][(w * 32 + 16) * 32]);
        const bf16* gb = Bt + (long)(n0 + w * 16 + lr4) * K + k0 + lc8;
        gload16(gb, &Bs[buf][(w * 16) * 32]);
    };

    STAGE(0, 0);
    __syncthreads();
    int nk = K >> 5;
    for (int it = 0; it < nk; ++it) {
        int cur = it & 1;
        if (it + 1 < nk) STAGE(cur ^ 1, (it + 1) << 5);
        bf16x8 af[4], bfr[2];
#pragma unroll
        for (int m = 0; m < 4; m++)
            af[m] = *(const bf16x8*)&As[cur][(wr * 64 + m * 16 + c) * 32 + g * 8];
#pragma unroll
        for (int n = 0; n < 2; n++)
            bfr[n] = *(const bf16x8*)&Bs[cur][(wc * 32 + n * 16 + c) * 32 + g * 8];
#pragma unroll
        for (int m = 0; m < 4; m++)
#pragma unroll
            for (int n = 0; n < 2; n++)
                acc[m][n] = mfma16(af[m], bfr[n], acc[m][n]);
        __syncthreads();
    }

    float bv[2] = {0.f, 0.f};
    if (BIAS) {
#pragma unroll
        for (int n = 0; n < 2; n++) bv[n] = bias[n0 + wc * 32 + n * 16 + c];
    }
    float* Cf = (float*)Cv;
    bf16* Cb = (bf16*)Cv;
#pragma unroll
    for (int m = 0; m < 4; m++)
#pragma unroll
        for (int n = 0; n < 2; n++)
#pragma unroll
            for (int j = 0; j < 4; j++) {
                long row = row0 + wr * 64 + m * 16 + g * 4 + j;
                int col = n0 + wc * 32 + n * 16 + c;
                float v = acc[m][n][j];
                if (BIAS) v += bv[n];
                if (RELU) v = fmaxf(v, 0.f);
                if (OUT_BF16) Cb[row * N + col] = (bf16)v;
                else Cf[row * N + col] = v;
            }
}

// ------------- 128x128 MFMA GEMM core (double-buffered) -------------
template<int OUT_BF16>
__device__ inline void gemm128_body(
    const bf16* __restrict__ Ab, const bf16* __restrict__ Bb,
    void* __restrict__ Cv, int N, int K, float scale,
    long row0, int n0)
{
    __shared__ bf16 As[2][4096];
    __shared__ bf16 Bs[2][4096];
    int tid = threadIdx.x;
    int lane = tid & 63, w = tid >> 6;
    int wr = w >> 1, wc = w & 1;
    int g = lane >> 4, c = lane & 15;

    f32x4 acc[4][4];
#pragma unroll
    for (int m = 0; m < 4; m++)
#pragma unroll
        for (int n = 0; n < 4; n++) acc[m][n] = (f32x4){0.f, 0.f, 0.f, 0.f};

    int lr4 = lane >> 2, lc8 = (lane & 3) * 8;
    auto STAGE = [&](int buf, int k0) {
        const bf16* ga = Ab + (row0 + w * 16 + lr4) * (long)K + k0 + lc8;
        gload16(ga, &As[buf][(w * 16) * 32]);
        gload16(ga + (long)64 * K, &As[buf][(w * 16 + 64) * 32]);
        const bf16* gb = Bb + (long)(n0 + w * 16 + lr4) * K + k0 + lc8;
        gload16(gb, &Bs[buf][(w * 16) * 32]);
        gload16(gb + (long)64 * K, &Bs[buf][(w * 16 + 64) * 32]);
    };

    STAGE(0, 0);
    __syncthreads();
    int nk = K >> 5;
    for (int it = 0; it < nk; ++it) {
        int cur = it & 1;
        if (it + 1 < nk) STAGE(cur ^ 1, (it + 1) << 5);
        bf16x8 af[4], bfr[4];
#pragma unroll
        for (int m = 0; m < 4; m++)
            af[m] = *(const bf16x8*)&As[cur][(wr * 64 + m * 16 + c) * 32 + g * 8];
#pragma unroll
        for (int n = 0; n < 4; n++)
            bfr[n] = *(const bf16x8*)&Bs[cur][(wc * 64 + n * 16 + c) * 32 + g * 8];
#pragma unroll
        for (int m = 0; m < 4; m++)
#pragma unroll
            for (int n = 0; n < 4; n++)
                acc[m][n] = mfma16(af[m], bfr[n], acc[m][n]);
        __syncthreads();
    }

    float* Cf = (float*)Cv;
    bf16* Cb = (bf16*)Cv;
#pragma unroll
    for (int m = 0; m < 4; m++)
#pragma unroll
        for (int n = 0; n < 4; n++)
#pragma unroll
            for (int j = 0; j < 4; j++) {
                long row = row0 + wr * 64 + m * 16 + g * 4 + j;
                int col = n0 + wc * 64 + n * 16 + c;
                float v = acc[m][n][j] * scale;
                if (OUT_BF16) Cb[row * N + col] = (bf16)v;
                else Cf[row * N + col] = v;
            }
}

// batched final-scores GEMM (fp32 out, scaled)
__global__ __launch_bounds__(256) void mfma_gemm128(
    const bf16* __restrict__ A, const bf16* __restrict__ Bt,
    float* __restrict__ Cv, int N, int K, float scale,
    long sA, long sB, long sC)
{
    long z = blockIdx.z;
    gemm128_body<0>(A + z * sA, Bt + z * sB, Cv + z * sC, N, K, scale,
                    (long)blockIdx.y * 128, blockIdx.x * 128);
}

// Q/K/V (z=3) or qf/kf (z=2) batched projections, 128x128 tiles.
// z==0 output scaled by scale0 (used to fold softmax scale into Q).
__global__ __launch_bounds__(256) void qkv_gemm(
    const bf16* __restrict__ Ah, const bf16* __restrict__ Ax,
    const bf16* __restrict__ B0, const bf16* __restrict__ B1,
    const bf16* __restrict__ B2,
    bf16* __restrict__ C0, bf16* __restrict__ C1, bf16* __restrict__ C2,
    float scale0)
{
    int z = blockIdx.z;
    if (z == 0 && blockIdx.y >= 32) return;
    const bf16* A = z ? Ax : Ah;
    const bf16* Bt = (z == 0) ? B0 : (z == 1 ? B1 : B2);
    bf16* C = (z == 0) ? C0 : (z == 1 ? C1 : C2);
    gemm128_body<1>(A, Bt, C, 512, 512, z == 0 ? scale0 : 1.f,
                    (long)blockIdx.y * 128, blockIdx.x * 128);
}

// ------------- MFMA flash attention (K+V in LDS, XCD-swizzled, exp2) -------------
// Q is pre-scaled by 0.125*log2e -> scores arrive in log2 domain.
__global__ __launch_bounds__(256, 4) void attn_mfma(
    const bf16* __restrict__ QP, const bf16* __restrict__ KP,
    const bf16* __restrict__ Vt, const unsigned* __restrict__ bits,
    bf16* __restrict__ Opart, float* __restrict__ Mpart,
    float* __restrict__ Lpart)
{
    __shared__ bf16 Kls[2][4096];      // [buf][64 keys x 64 d], swizzled
    __shared__ bf16 Vls[2][4096];      // [buf][64 d x 64 keys], swizzled
    __shared__ bf16 Pl[4][1024];       // per-wave P [q=c][64 keys], XOR-swizzled

    int tid = threadIdx.x;
    int lane = tid & 63, wv = tid >> 6;
    int g = lane >> 4, c = lane & 15;

    int flat = blockIdx.x;
    int logical = (flat & 7) * 128 + (flat >> 3);   // XCD-chunked
    int bh = logical >> 5;
    int rr = logical & 31;
    int sp = rr >> 4;
    int q0 = (rr & 15) * 64 + wv * 16;
    int b = bh >> 3;

    long qrow0 = (long)bh * 1024 + q0;
    long krow0 = (long)bh * 2048 + (long)sp * 1024;
    const bf16* vtb = Vt + (long)bh * 131072 + (long)sp * 1024;
    const unsigned* bitrow = bits + ((long)b * 1024 + q0 + c) * 64 + sp * 32;

    int lr = lane >> 3, lc = lane & 7;
    int scol = (lc ^ lr) * 8;                       // pre-swizzled src col
    int cs = c & 7;

    bf16x8 qa[2];
#pragma unroll
    for (int hh = 0; hh < 2; hh++)
        qa[hh] = *(const bf16x8*)(QP + (qrow0 + c) * 64 + hh * 32 + g * 8);

    f32x4 o_acc[4];
#pragma unroll
    for (int ot = 0; ot < 4; ot++) o_acc[ot] = (f32x4){0.f, 0.f, 0.f, 0.f};
    float m_r = -1e30f, l_r = 0.f;

    {
        const bf16* sk = KP + (krow0 + wv * 16 + lr) * 64 + scol;
        gload16(sk, &Kls[0][(wv * 16) * 64]);
        gload16(sk + 8 * 64, &Kls[0][(wv * 16 + 8) * 64]);
        const bf16* sv = vtb + (long)(wv * 16 + lr) * 2048 + scol;
        gload16(sv, &Vls[0][(wv * 16) * 64]);
        gload16(sv + 8 * 2048, &Vls[0][(wv * 16 + 8) * 64]);
    }
    uint2 wp_nxt = *(const uint2*)(bitrow);
    __syncthreads();

    const int NT = LKK / KSPLIT / 64;   // 16
    for (int kt = 0; kt < NT; kt++) {
        int cur = kt & 1;
        if (kt + 1 < NT) {
            int kn = (kt + 1) * 64;
            const bf16* sk = KP + (krow0 + kn + wv * 16 + lr) * 64 + scol;
            gload16(sk, &Kls[cur ^ 1][(wv * 16) * 64]);
            gload16(sk + 8 * 64, &Kls[cur ^ 1][(wv * 16 + 8) * 64]);
            const bf16* sv = vtb + (long)(wv * 16 + lr) * 2048 + kn + scol;
            gload16(sv, &Vls[cur ^ 1][(wv * 16) * 64]);
            gload16(sv + 8 * 2048, &Vls[cur ^ 1][(wv * 16 + 8) * 64]);
        }
        uint2 wp = wp_nxt;
        if (kt + 1 < NT) wp_nxt = *(const uint2*)(bitrow + (kt + 1) * 2);

        // S^T = K Q^T from LDS (swizzled read); already log2-domain
        const char* kls = (const char*)&Kls[cur][0];
        f32x4 s[4];
#pragma unroll
        for (int mt = 0; mt < 4; mt++) {
            bf16x8 ka0 = *(const bf16x8*)(kls + (mt * 16 + c) * 128 + ((g ^ cs) << 4));
            bf16x8 ka1 = *(const bf16x8*)(kls + (mt * 16 + c) * 128 + (((4 + g) ^ cs) << 4));
            s[mt] = mfma16(ka0, qa[0], (f32x4){0.f, 0.f, 0.f, 0.f});
            s[mt] = mfma16(ka1, qa[1], s[mt]);
        }

        // mask (select only; scale already folded into Q)
#pragma unroll
        for (int mt = 0; mt < 4; mt++)
#pragma unroll
            for (int j = 0; j < 4; j++) {
                int kl = mt * 16 + 4 * g + j;
                unsigned wsel = (kl < 32) ? wp.x : wp.y;
                if ((wsel >> (kl & 31)) & 1) s[mt][j] = -1e30f;
            }

        // online softmax (log2 domain) with defer-max (THR = 8*log2e)
        float mx = -1e30f;
#pragma unroll
        for (int mt = 0; mt < 4; mt++)
            mx = fmaxf(mx, fmaxf(fmaxf(s[mt][0], s[mt][1]),
                                 fmaxf(s[mt][2], s[mt][3])));
        mx = fmaxf(mx, __shfl_xor(mx, 16, 64));
        mx = fmaxf(mx, __shfl_xor(mx, 32, 64));

        float fct = 1.f;
        if (__any(mx > m_r + 11.5415f)) {
            float mnew = fmaxf(m_r, mx);
            fct = fexp2(m_r - mnew);
            m_r = mnew;
            float fq[4];
#pragma unroll
            for (int j = 0; j < 4; j++)
                fq[j] = __shfl(fct, (lane & 48) | (4 * g + j), 64);
#pragma unroll
            for (int ot = 0; ot < 4; ot++)
#pragma unroll
                for (int j = 0; j < 4; j++) o_acc[ot][j] *= fq[j];
        }

        float sum = 0.f;
#pragma unroll
        for (int mt = 0; mt < 4; mt++)
#pragma unroll
            for (int j = 0; j < 4; j++) {
                float p = fexp2(s[mt][j] - m_r);
                s[mt][j] = p;
                sum += p;
            }
        sum += __shfl_xor(sum, 16, 64);
        sum += __shfl_xor(sum, 32, 64);
        l_r = l_r * fct + sum;

        // P -> per-wave LDS, XOR-swizzled
        char* plb = (char*)&Pl[wv][0];
#pragma unroll
        for (int mt = 0; mt < 4; mt++) {
            bf16x4 pk;
#pragma unroll
            for (int j = 0; j < 4; j++) pk[j] = (bf16)s[mt][j];
            int wch = (mt * 2 + (g >> 1)) ^ cs;
            *(bf16x4*)(plb + c * 128 + (wch << 4) + (g & 1) * 8) = pk;
        }

        // PV
        const char* vls = (const char*)&Vls[cur][0];
#pragma unroll
        for (int kh = 0; kh < 2; kh++) {
            bf16x8 pa = *(const bf16x8*)(plb + c * 128 + ((((kh << 2) + g) ^ cs) << 4));
#pragma unroll
            for (int ot = 0; ot < 4; ot++) {
                bf16x8 vbf = *(const bf16x8*)
                    (vls + (ot * 16 + c) * 128 + ((((kh << 2) + g) ^ cs) << 4));
                o_acc[ot] = mfma16(pa, vbf, o_acc[ot]);
            }
        }
        __syncthreads();
    }

    long ob = ((long)sp * NROWS + qrow0) * 64;
#pragma unroll
    for (int ot = 0; ot < 4; ot++)
#pragma unroll
        for (int j = 0; j < 4; j++)
            Opart[ob + (long)(4 * g + j) * 64 + ot * 16 + c] = (bf16)o_acc[ot][j];
    if (g == 0) {
        Mpart[(long)sp * NROWS + qrow0 + c] = m_r;
        Lpart[(long)sp * NROWS + qrow0 + c] = l_r;
    }
}

// ------------- combine k-split partials (log2-domain stats) -------------
__global__ __launch_bounds__(256) void attn_combine(
    const bf16* __restrict__ Op, const float* __restrict__ Mp,
    const float* __restrict__ Lp, bf16* __restrict__ O)
{
    long idx = (long)blockIdx.x * 256 + threadIdx.x;
    long row = idx >> 6;
    float m0 = Mp[row], m1 = Mp[NROWS + row];
    float l0 = Lp[row], l1 = Lp[NROWS + row];
    float mm = fmaxf(m0, m1);
    float e0 = fexp2(m0 - mm), e1 = fexp2(m1 - mm);
    float inv = 1.f / (l0 * e0 + l1 * e1);
    float o = ((float)Op[idx] * e0 + (float)Op[(long)NROWS * 64 + idx] * e1) * inv;
    O[idx] = (bf16)o;
}

// ------------- LN(residual) -------------
__global__ __launch_bounds__(256) void ln_kernel(
    const float* __restrict__ res, const float* __restrict__ y,
    const float* __restrict__ g, const float* __restrict__ bb,
    float* __restrict__ outf, bf16* __restrict__ outb)
{
    int wave = threadIdx.x >> 6, lane = threadIdx.x & 63;
    long row = (long)blockIdx.x * 4 + wave;
    const float* rp = res + row * D_MODEL;
    const float* yp = y + row * D_MODEL;
    float v[8];
    float s = 0.f, sq = 0.f;
#pragma unroll
    for (int j = 0; j < 8; j++) {
        int col = lane + 64 * j;
        v[j] = rp[col] + yp[col];
        s += v[j]; sq += v[j] * v[j];
    }
#pragma unroll
    for (int o = 32; o > 0; o >>= 1) {
        s += __shfl_down(s, o, 64);
        sq += __shfl_down(sq, o, 64);
    }
    s = __shfl(s, 0, 64);
    sq = __shfl(sq, 0, 64);
    float mean = s * (1.f / 512.f);
    float var = sq * (1.f / 512.f) - mean * mean;
    float rstd = rsqrtf(fmaxf(var, 0.f) + 1e-5f);
    float* opf = outf + row * D_MODEL;
    bf16* opb = outb + row * D_MODEL;
#pragma unroll
    for (int j = 0; j < 8; j++) {
        int col = lane + 64 * j;
        float o = (v[j] - mean) * rstd * g[col] + bb[col];
        opf[col] = o;
        opb[col] = (bf16)o;
    }
}

extern "C" void kernel_launch(void* const* d_in, const int* in_sizes, int n_in,
                              void* d_out, int out_size, void* d_ws, size_t ws_size,
                              hipStream_t stream)
{
    const float* x    = (const float*)d_in[0];
    const float* hin  = (const float*)d_in[1];
    const int*   mask = (const int*)d_in[2];
    const float* wq   = (const float*)d_in[3];
    const float* wk   = (const float*)d_in[4];
    const float* wv   = (const float*)d_in[5];
    const float* wo   = (const float*)d_in[6];
    const float* ffw1 = (const float*)d_in[7];
    const float* ffb1 = (const float*)d_in[8];
    const float* ffw2 = (const float*)d_in[9];
    const float* ffb2 = (const float*)d_in[10];
    const float* g1   = (const float*)d_in[11];
    const float* be1  = (const float*)d_in[12];
    const float* g2   = (const float*)d_in[13];
    const float* be2  = (const float*)d_in[14];
    const float* out_wq = (const float*)d_in[15];
    const float* out_wk = (const float*)d_in[16];
    float* out = (float*)d_out;

    const long NQ = (long)BB * LQ;   // 4096
    const long NK = (long)BB * LKK;  // 8192

    // workspace layout (bytes). SH region time-shares y_f / V-plane / Opart.
    char* W = (char*)d_ws;
    float* h_f  = (float*)(W);                      // 8 MB
    char*  SH   = W + 8388608;                      // 8 MB shared region
    float* y_f  = (float*)SH;
    bf16*  v_pl = (bf16*)SH;
    bf16*  opart= (bf16*)SH;
    bf16*  h_b  = (bf16*)(W + 16777216);            // 4 MB
    bf16*  x_b  = (bf16*)(W + 20971520);            // 8 MB
    bf16*  q_b  = (bf16*)(W + 29360128);            // 4 MB
    bf16*  a_b  = (bf16*)(W + 33554432);            // 4 MB
    bf16*  k_pl = (bf16*)(W + 37748736);            // 8 MB
    bf16*  vt   = (bf16*)(W + 46137344);            // 8 MB
    bf16*  wts  = (bf16*)(W + 54525952);            // 19 matrices (9.5 MB)
    bf16*  wtOQ = wts + 19 * WSZC;                  // +0.5 MB
    unsigned* mb = (unsigned*)(W + 65011712);       // 1 MB
    float* Mpart = (float*)(W + 66060288);          // 256 KB
    float* Lpart = (float*)(W + 66322432);          // 256 KB

    dim3 blk(256);

    // preprocessing
    hipMemcpyAsync(h_f, hin, NQ * D_MODEL * sizeof(float),
                   hipMemcpyDeviceToDevice, stream);
    cast_kernel<<<dim3((NK * D_MODEL / 4 + 255) / 256), blk, 0, stream>>>(x, x_b, NK * D_MODEL);
    cast_kernel<<<dim3((NQ * D_MODEL / 4 + 255) / 256), blk, 0, stream>>>(hin, h_b, NQ * D_MODEL);
    tcast_all<<<dim3(16, 16, 20), blk, 0, stream>>>(
        wq, wo, ffw1, ffw2, wk, wv, out_wq, out_wk, wts, wtOQ);
    maskbits_kernel<<<dim3(32768), blk, 0, stream>>>(mask, mb);

    dim3 gq(8, 32, 1);           // 4096 x 512 (128x64)
    dim3 gqkv(4, 64, 3);         // z: Q(4096) / K(8192) / V(8192), 128x128
    dim3 gvt(32, 32);
    dim3 ga(1024);               // flat, XCD-swizzled inside
    dim3 gc(NROWS * 64 / 256);

    const float C2 = 0.1803368801111243f;   // 0.125 * log2(e)

    for (int i = 0; i < NL; i++) {
        qkv_gemm<<<gqkv, blk, 0, stream>>>(h_b, x_b,
            wts + i * WSZC, wts + (12 + 2 * i) * WSZC, wts + (13 + 2 * i) * WSZC,
            q_b, k_pl, v_pl, C2);
        vtrans_kernel<<<gvt, blk, 0, stream>>>(v_pl, vt);

        attn_mfma<<<ga, blk, 0, stream>>>(q_b, k_pl, vt, mb, opart, Mpart, Lpart);
        attn_combine<<<gc, blk, 0, stream>>>(opart, Mpart, Lpart, a_b);

        mfma_gemm<0,0,0><<<gq, blk, 0, stream>>>(a_b, wts + (3 + i) * WSZC,
            nullptr, y_f, 512, 512);
        ln_kernel<<<dim3(NQ / 4), blk, 0, stream>>>(h_f, y_f,
            g1 + i * D_MODEL, be1 + i * D_MODEL, h_f, h_b);

        mfma_gemm<1,1,1><<<gq, blk, 0, stream>>>(h_b, wts + (6 + i) * WSZC,
            ffb1 + i * D_MODEL, q_b, 512, 512);
        mfma_gemm<1,0,0><<<gq, blk, 0, stream>>>(q_b, wts + (9 + i) * WSZC,
            ffb2 + i * D_MODEL, y_f, 512, 512);
        ln_kernel<<<dim3(NQ / 4), blk, 0, stream>>>(h_f, y_f,
            g2 + i * D_MODEL, be2 + i * D_MODEL, h_f, h_b);
    }

    // final: qf = h@out_wq (z=0, unscaled), kf = x@out_wk (z=1)
    dim3 gqk(4, 64, 2);
    qkv_gemm<<<gqk, blk, 0, stream>>>(h_b, x_b,
        wtOQ, wts + 18 * WSZC, wts + 18 * WSZC, q_b, k_pl, k_pl, 1.f);

    dim3 gf(LKK / 128, LQ / 128, BB);
    mfma_gemm128<<<gf, blk, 0, stream>>>(q_b, k_pl, out,
        LKK, 512, 0.04419417382415922f,
        (long)LQ * 512, (long)LKK * 512, (long)LQ * LKK);
}